// Round 11
// baseline (475.153 us; speedup 1.0000x reference)
//
#include <hip/hip_runtime.h>

#define NN 50000
#define NE 600000
#define DD 128
#define XS 264   // padded LDS row stride in bf16 elems: 528 B = 132 fp32 (exact fp32 reuse for m-buffer)
#define NB 49    // scan blocks: ceil(NN/1024)

typedef unsigned short u16;
typedef u16   u16x8  __attribute__((ext_vector_type(8)));
typedef u16   u16x4  __attribute__((ext_vector_type(4)));
typedef __bf16 bf16x8 __attribute__((ext_vector_type(8)));
typedef float f32x4  __attribute__((ext_vector_type(4)));

__device__ __forceinline__ u16 f2bf(float f) {  // RNE fp32->bf16
    unsigned u = __builtin_bit_cast(unsigned, f);
    u += 0x7FFFu + ((u >> 16) & 1u);
    return (u16)(u >> 16);
}

// node_features fp32 [NN,DD] -> bf16 table
__global__ void k_convert_nf(const float* __restrict__ nf, u16* __restrict__ out) {
    int id = blockIdx.x * 256 + threadIdx.x;            // NN*DD/4 threads exactly
    float4 v = ((const float4*)nf)[id];
    u16x4 o; o[0] = f2bf(v.x); o[1] = f2bf(v.y); o[2] = f2bf(v.z); o[3] = f2bf(v.w);
    ((u16x4*)out)[id] = o;
}

// Pack W[K,N] fp32 row-major into MFMA B-fragment order for 16x16x32
__global__ void k_pack(const float* __restrict__ W, u16* __restrict__ out, int K, int N) {
    int tid = blockIdx.x * 256 + threadIdx.x;
    if (tid >= K * N) return;
    int frag = tid >> 9, lane = (tid >> 3) & 63, j = tid & 7;
    int KT = K >> 5;
    int nt = frag / KT, kt = frag - nt * KT;
    int row = kt * 32 + ((lane >> 4) << 3) + j;
    int col = nt * 16 + (lane & 15);
    out[tid] = f2bf(W[row * N + col]);
}

// ---------------- counting sort of edges by destination (multi-block scan; validated r7) ----------------
__global__ void k_hist(const int* __restrict__ to_idx, int* __restrict__ cnt) {
    int e = blockIdx.x * 256 + threadIdx.x;
    if (e < NE) atomicAdd(&cnt[to_idx[e]], 1);
}

__global__ void k_scanA(const int* __restrict__ cnt, int* __restrict__ part, int* __restrict__ bsum) {
    __shared__ int s[1024];
    int tid = threadIdx.x;
    int g = blockIdx.x * 1024 + tid;
    int v = (g < NN) ? cnt[g] : 0;
    s[tid] = v;
    __syncthreads();
    for (int ofs = 1; ofs < 1024; ofs <<= 1) {
        int t = (tid >= ofs) ? s[tid - ofs] : 0;
        __syncthreads();
        s[tid] += t;
        __syncthreads();
    }
    if (g < NN) part[g] = s[tid] - v;           // exclusive within block
    if (tid == 1023) bsum[blockIdx.x] = s[1023];
}

__global__ void k_scanB(int* __restrict__ bsum) {
    __shared__ int s[64];
    int tid = threadIdx.x;
    int v = (tid < NB) ? bsum[tid] : 0;
    s[tid] = v;
    __syncthreads();
    for (int ofs = 1; ofs < 64; ofs <<= 1) {
        int t = (tid >= ofs) ? s[tid - ofs] : 0;
        __syncthreads();
        s[tid] += t;
        __syncthreads();
    }
    if (tid < NB) bsum[tid] = s[tid] - v;       // exclusive
}

__global__ void k_scanC(const int* __restrict__ part, const int* __restrict__ bsum, int* __restrict__ cursor) {
    int g = blockIdx.x * 256 + threadIdx.x;
    if (g < NN) cursor[g] = part[g] + bsum[g >> 10];
}

__global__ void k_reorder(const int* __restrict__ from_idx, const int* __restrict__ to_idx,
                          int* __restrict__ cursor, int* __restrict__ sf, int* __restrict__ st) {
    int e = blockIdx.x * 256 + threadIdx.x;
    if (e < NE) {
        int d = to_idx[e];
        int p = atomicAdd(&cursor[d], 1);
        sf[p] = from_idx[e];
        st[p] = d;
    }
}

// ---------------- edge kernel v9: v8 + B-frag prefetch headroom (launch_bounds(128,2) + unroll 2) ----------------
// v8 validated: sorted edges + block segmented reduction (WRITE 131->29 MB, 244us). Remaining
// invariant across ALL flat variants: nt-loop loads 8 B-frags then waits (~250cy L2) before 16
// MFMAs, no prefetch possible at VGPR=88. (128,2) raises VGPR cap to 256; unroll 2 puts two
// iterations' loads in flight over each MFMA burst.
__global__ __launch_bounds__(128, 2) void k_edges(
    const u16* __restrict__ nf16, const int* __restrict__ sf,
    const int* __restrict__ st, const u16* __restrict__ pW0,
    const float* __restrict__ b0, const u16* __restrict__ pW1,
    const float* __restrict__ b1, float* __restrict__ agg)
{
    __shared__ u16 sX[64 * XS];
    __shared__ int sDest[64];
    const int tid = threadIdx.x;
    const int e0 = blockIdx.x * 64;

    if (tid < 64) sDest[tid] = st[e0 + tid];
    // stage gather: 64 rows x 32 chunks of 8 bf16 (16 B); to-side rows repeat (sorted) -> cache-hot
    #pragma unroll
    for (int i = 0; i < 16; ++i) {
        int c = i * 128 + tid;
        int r = c >> 5, j = c & 31;
        int e = e0 + r;
        int node = (j < 16) ? sf[e] : st[e];
        *(u16x8*)(&sX[r * XS + j * 8]) = *(const u16x8*)(nf16 + node * DD + (j & 15) * 8);
    }
    __syncthreads();

    const int lane = tid & 63;
    const int wave = tid >> 6;
    const int base = wave * 32;
    const int l15  = lane & 15;
    const int quad = lane >> 4;
    const int arow0 = (base + l15) * XS + quad * 8;

    // consume X fully into registers (A-frags), freeing sX rows for H (rows wave-private)
    bf16x8 a[2][8];
    #pragma unroll
    for (int mt = 0; mt < 2; ++mt)
        #pragma unroll
        for (int kt = 0; kt < 8; ++kt)
            a[mt][kt] = __builtin_bit_cast(bf16x8, *(const u16x8*)(&sX[arow0 + mt * 16 * XS + kt * 32]));

    // layer 0: H[64,256] = relu(X @ W0 + b0); unroll 2 -> 16 B-frag loads in flight per MFMA burst
    #pragma unroll 2
    for (int nt = 0; nt < 16; ++nt) {
        f32x4 c0 = {0.f, 0.f, 0.f, 0.f}, c1 = {0.f, 0.f, 0.f, 0.f};
        #pragma unroll
        for (int kt = 0; kt < 8; ++kt) {
            bf16x8 b = __builtin_bit_cast(bf16x8, *(const u16x8*)(pW0 + (nt * 8 + kt) * 512 + lane * 8));
            c0 = __builtin_amdgcn_mfma_f32_16x16x32_bf16(a[0][kt], b, c0, 0, 0, 0);
            c1 = __builtin_amdgcn_mfma_f32_16x16x32_bf16(a[1][kt], b, c1, 0, 0, 0);
        }
        float bias = b0[nt * 16 + l15];
        #pragma unroll
        for (int i = 0; i < 4; ++i) {
            sX[(base +      quad * 4 + i) * XS + nt * 16 + l15] = f2bf(fmaxf(c0[i] + bias, 0.f));
            sX[(base + 16 + quad * 4 + i) * XS + nt * 16 + l15] = f2bf(fmaxf(c1[i] + bias, 0.f));
        }
    }

    // layer 1 A-frags from H (same rows, in-wave ordered: no barrier needed)
    #pragma unroll
    for (int mt = 0; mt < 2; ++mt)
        #pragma unroll
        for (int kt = 0; kt < 8; ++kt)
            a[mt][kt] = __builtin_bit_cast(bf16x8, *(const u16x8*)(&sX[arow0 + mt * 16 * XS + kt * 32]));

    __syncthreads();   // fence: u16 H-reads above must complete before fp32 m-writes below (TBAA)

    // layer 1: m = relu(H @ W1 + b1) -> fp32 into sM (reuses sX bytes; rows wave-private)
    float* sM = (float*)sX;   // [64][132] fp32 view, 132*4 = 264*2 bytes ✓
    #pragma unroll 2
    for (int nt = 0; nt < 8; ++nt) {
        f32x4 c0 = {0.f, 0.f, 0.f, 0.f}, c1 = {0.f, 0.f, 0.f, 0.f};
        #pragma unroll
        for (int kt = 0; kt < 8; ++kt) {
            bf16x8 b = __builtin_bit_cast(bf16x8, *(const u16x8*)(pW1 + (nt * 8 + kt) * 512 + lane * 8));
            c0 = __builtin_amdgcn_mfma_f32_16x16x32_bf16(a[0][kt], b, c0, 0, 0, 0);
            c1 = __builtin_amdgcn_mfma_f32_16x16x32_bf16(a[1][kt], b, c1, 0, 0, 0);
        }
        float bias = b1[nt * 16 + l15];
        int col = nt * 16 + l15;
        #pragma unroll
        for (int i = 0; i < 4; ++i) {
            sM[(base +      quad * 4 + i) * 132 + col] = fmaxf(c0[i] + bias, 0.f);
            sM[(base + 16 + quad * 4 + i) * 132 + col] = fmaxf(c1[i] + bias, 0.f);
        }
    }
    __syncthreads();

    // block-wide segmented reduction over 64 sorted rows; thread = column (128 cols)
    const int head_d = sDest[0];
    const int tail_d = sDest[63];
    const bool head_sh = (e0 > 0) && (st[e0 - 1] == head_d);
    const bool tail_sh = (e0 + 64 < NE) && (st[e0 + 64] == tail_d);

    int dprev = head_d;
    float acc = sM[tid];          // row 0
    for (int r = 1; r < 64; ++r) {
        int d = sDest[r];         // wave-uniform -> uniform branch
        float v = sM[r * 132 + tid];
        if (d == dprev) acc += v;
        else {
            if ((dprev == head_d && head_sh) || (dprev == tail_d && tail_sh))
                unsafeAtomicAdd(&agg[(size_t)dprev * DD + tid], acc);
            else
                agg[(size_t)dprev * DD + tid] = acc;   // sole writer (interior run)
            acc = v; dprev = d;
        }
    }
    if ((dprev == head_d && head_sh) || (dprev == tail_d && tail_sh))
        unsafeAtomicAdd(&agg[(size_t)dprev * DD + tid], acc);
    else
        agg[(size_t)dprev * DD + tid] = acc;
}

// Node update: r7-validated structure + same prefetch headroom
__global__ __launch_bounds__(128, 2) void k_update(
    const float* __restrict__ agg, const u16* __restrict__ nf16,
    const float* __restrict__ nf32, const u16* __restrict__ pW0,
    const float* __restrict__ b0, const u16* __restrict__ pW1,
    const float* __restrict__ b1, float* __restrict__ out)
{
    __shared__ u16 sX[64 * XS];
    const int tid = threadIdx.x;
    const int n0 = blockIdx.x * 64;

    // stage agg half (cols 0..127), fp32->bf16
    #pragma unroll
    for (int i = 0; i < 16; ++i) {
        int c = i * 128 + tid;
        int r = c >> 5, j = c & 31;
        int n = n0 + r;
        u16x4 o;
        if (n < NN) {
            float4 v = *(const float4*)(agg + (size_t)n * DD + j * 4);
            o[0] = f2bf(v.x); o[1] = f2bf(v.y); o[2] = f2bf(v.z); o[3] = f2bf(v.w);
        } else { o[0] = 0; o[1] = 0; o[2] = 0; o[3] = 0; }
        *(u16x4*)(&sX[r * XS + j * 4]) = o;
    }
    // stage nf half (cols 128..255), bf16 copy
    #pragma unroll
    for (int i = 0; i < 8; ++i) {
        int c = i * 128 + tid;
        int r = c >> 4, j = c & 15;
        int n = n0 + r;
        u16x8 v = {0, 0, 0, 0, 0, 0, 0, 0};
        if (n < NN) v = *(const u16x8*)(nf16 + (size_t)n * DD + j * 8);
        *(u16x8*)(&sX[r * XS + 128 + j * 8]) = v;
    }
    __syncthreads();

    const int lane = tid & 63;
    const int wave = tid >> 6;
    const int base = wave * 32;
    const int l15  = lane & 15;
    const int quad = lane >> 4;
    const int arow0 = (base + l15) * XS + quad * 8;

    bf16x8 a[2][8];
    #pragma unroll
    for (int mt = 0; mt < 2; ++mt)
        #pragma unroll
        for (int kt = 0; kt < 8; ++kt)
            a[mt][kt] = __builtin_bit_cast(bf16x8, *(const u16x8*)(&sX[arow0 + mt * 16 * XS + kt * 32]));

    #pragma unroll 2
    for (int nt = 0; nt < 16; ++nt) {
        f32x4 c0 = {0.f, 0.f, 0.f, 0.f}, c1 = {0.f, 0.f, 0.f, 0.f};
        #pragma unroll
        for (int kt = 0; kt < 8; ++kt) {
            bf16x8 b = __builtin_bit_cast(bf16x8, *(const u16x8*)(pW0 + (nt * 8 + kt) * 512 + lane * 8));
            c0 = __builtin_amdgcn_mfma_f32_16x16x32_bf16(a[0][kt], b, c0, 0, 0, 0);
            c1 = __builtin_amdgcn_mfma_f32_16x16x32_bf16(a[1][kt], b, c1, 0, 0, 0);
        }
        float bias = b0[nt * 16 + l15];
        #pragma unroll
        for (int i = 0; i < 4; ++i) {
            sX[(base +      quad * 4 + i) * XS + nt * 16 + l15] = f2bf(fmaxf(c0[i] + bias, 0.f));
            sX[(base + 16 + quad * 4 + i) * XS + nt * 16 + l15] = f2bf(fmaxf(c1[i] + bias, 0.f));
        }
    }

    #pragma unroll
    for (int mt = 0; mt < 2; ++mt)
        #pragma unroll
        for (int kt = 0; kt < 8; ++kt)
            a[mt][kt] = __builtin_bit_cast(bf16x8, *(const u16x8*)(&sX[arow0 + mt * 16 * XS + kt * 32]));

    #pragma unroll 2
    for (int nt = 0; nt < 8; ++nt) {
        f32x4 c0 = {0.f, 0.f, 0.f, 0.f}, c1 = {0.f, 0.f, 0.f, 0.f};
        #pragma unroll
        for (int kt = 0; kt < 8; ++kt) {
            bf16x8 b = __builtin_bit_cast(bf16x8, *(const u16x8*)(pW1 + (nt * 8 + kt) * 512 + lane * 8));
            c0 = __builtin_amdgcn_mfma_f32_16x16x32_bf16(a[0][kt], b, c0, 0, 0, 0);
            c1 = __builtin_amdgcn_mfma_f32_16x16x32_bf16(a[1][kt], b, c1, 0, 0, 0);
        }
        float bias = b1[nt * 16 + l15];
        int col = nt * 16 + l15;
        #pragma unroll
        for (int i = 0; i < 4; ++i) {
            int na = n0 + base +      quad * 4 + i;
            int nb = n0 + base + 16 + quad * 4 + i;
            if (na < NN) out[(size_t)na * DD + col] = nf32[(size_t)na * DD + col] + fmaxf(c0[i] + bias, 0.f);
            if (nb < NN) out[(size_t)nb * DD + col] = nf32[(size_t)nb * DD + col] + fmaxf(c1[i] + bias, 0.f);
        }
    }
}

extern "C" void kernel_launch(void* const* d_in, const int* in_sizes, int n_in,
                              void* d_out, int out_size, void* d_ws, size_t ws_size,
                              hipStream_t stream)
{
    const float* nf  = (const float*)d_in[0];
    const int* fidx  = (const int*)d_in[1];
    const int* tidx  = (const int*)d_in[2];
    const float* mW0 = (const float*)d_in[3];
    const float* mb0 = (const float*)d_in[4];
    const float* mW1 = (const float*)d_in[5];
    const float* mb1 = (const float*)d_in[6];
    const float* uW0 = (const float*)d_in[7];
    const float* ub0 = (const float*)d_in[8];
    const float* uW1 = (const float*)d_in[9];
    const float* ub1 = (const float*)d_in[10];
    float* out = (float*)d_out;

    char* ws = (char*)d_ws;
    u16*   nf16 = (u16*)ws;   ws += (size_t)NN * DD * 2;   // 12.8 MB
    float* agg  = (float*)ws; ws += (size_t)NN * DD * 4;   // 25.6 MB
    u16*   pmW0 = (u16*)ws;   ws += 256 * 256 * 2;
    u16*   pmW1 = (u16*)ws;   ws += 256 * 128 * 2;
    u16*   puW0 = (u16*)ws;   ws += 256 * 256 * 2;
    u16*   puW1 = (u16*)ws;   ws += 256 * 128 * 2;
    int*   cnt    = (int*)ws; ws += (size_t)NN * 4;        // 0.2 MB
    int*   cursor = (int*)ws; ws += (size_t)NN * 4;        // 0.2 MB
    int*   part   = (int*)ws; ws += (size_t)NN * 4;        // 0.2 MB
    int*   bsum   = (int*)ws; ws += 64 * 4;
    int*   sf     = (int*)ws; ws += (size_t)NE * 4;        // 2.4 MB
    int*   st     = (int*)ws; ws += (size_t)NE * 4;        // 2.4 MB

    hipMemsetAsync(agg, 0, (size_t)NN * DD * 4, stream);
    hipMemsetAsync(cnt, 0, (size_t)NN * 4, stream);
    k_convert_nf<<<(NN * DD / 4) / 256, 256, 0, stream>>>(nf, nf16);
    k_pack<<<256, 256, 0, stream>>>(mW0, pmW0, 256, 256);
    k_pack<<<128, 256, 0, stream>>>(mW1, pmW1, 256, 128);
    k_pack<<<256, 256, 0, stream>>>(uW0, puW0, 256, 256);
    k_pack<<<128, 256, 0, stream>>>(uW1, puW1, 256, 128);
    k_hist<<<(NE + 255) / 256, 256, 0, stream>>>(tidx, cnt);
    k_scanA<<<NB, 1024, 0, stream>>>(cnt, part, bsum);
    k_scanB<<<1, 64, 0, stream>>>(bsum);
    k_scanC<<<(NN + 255) / 256, 256, 0, stream>>>(part, bsum, cursor);
    k_reorder<<<(NE + 255) / 256, 256, 0, stream>>>(fidx, tidx, cursor, sf, st);
    k_edges<<<NE / 64, 128, 0, stream>>>(nf16, sf, st, pmW0, mb0, pmW1, mb1, agg);
    k_update<<<(NN + 63) / 64, 128, 0, stream>>>(agg, nf16, nf, puW0, ub0, puW1, ub1, out);
}

// Round 12
// 386.986 us; speedup vs baseline: 1.2278x; 1.2278x over previous
//
#include <hip/hip_runtime.h>

#define NN 50000
#define NE 600000
#define DD 128
#define XS 264   // padded LDS row stride in bf16 elems: 528 B = 132 fp32 (exact fp32 reuse for m-buffer)
#define NB 49    // scan blocks: ceil(NN/1024)

typedef unsigned short u16;
typedef u16   u16x8  __attribute__((ext_vector_type(8)));
typedef u16   u16x4  __attribute__((ext_vector_type(4)));
typedef __bf16 bf16x8 __attribute__((ext_vector_type(8)));
typedef float f32x4  __attribute__((ext_vector_type(4)));

__device__ __forceinline__ u16 f2bf(float f) {  // RNE fp32->bf16
    unsigned u = __builtin_bit_cast(unsigned, f);
    u += 0x7FFFu + ((u >> 16) & 1u);
    return (u16)(u >> 16);
}

// load one nt-column of packed W into 8 named B-frag registers
__device__ __forceinline__ void loadB(bf16x8 (&d)[8], const u16* __restrict__ pw, int nt, int lane) {
    #pragma unroll
    for (int kt = 0; kt < 8; ++kt)
        d[kt] = __builtin_bit_cast(bf16x8, *(const u16x8*)(pw + (nt * 8 + kt) * 512 + lane * 8));
}

// node_features fp32 [NN,DD] -> bf16 table
__global__ void k_convert_nf(const float* __restrict__ nf, u16* __restrict__ out) {
    int id = blockIdx.x * 256 + threadIdx.x;            // NN*DD/4 threads exactly
    float4 v = ((const float4*)nf)[id];
    u16x4 o; o[0] = f2bf(v.x); o[1] = f2bf(v.y); o[2] = f2bf(v.z); o[3] = f2bf(v.w);
    ((u16x4*)out)[id] = o;
}

// Pack W[K,N] fp32 row-major into MFMA B-fragment order for 16x16x32
__global__ void k_pack(const float* __restrict__ W, u16* __restrict__ out, int K, int N) {
    int tid = blockIdx.x * 256 + threadIdx.x;
    if (tid >= K * N) return;
    int frag = tid >> 9, lane = (tid >> 3) & 63, j = tid & 7;
    int KT = K >> 5;
    int nt = frag / KT, kt = frag - nt * KT;
    int row = kt * 32 + ((lane >> 4) << 3) + j;
    int col = nt * 16 + (lane & 15);
    out[tid] = f2bf(W[row * N + col]);
}

// ---------------- counting sort of edges by destination (multi-block scan; validated r7) ----------------
__global__ void k_hist(const int* __restrict__ to_idx, int* __restrict__ cnt) {
    int e = blockIdx.x * 256 + threadIdx.x;
    if (e < NE) atomicAdd(&cnt[to_idx[e]], 1);
}

__global__ void k_scanA(const int* __restrict__ cnt, int* __restrict__ part, int* __restrict__ bsum) {
    __shared__ int s[1024];
    int tid = threadIdx.x;
    int g = blockIdx.x * 1024 + tid;
    int v = (g < NN) ? cnt[g] : 0;
    s[tid] = v;
    __syncthreads();
    for (int ofs = 1; ofs < 1024; ofs <<= 1) {
        int t = (tid >= ofs) ? s[tid - ofs] : 0;
        __syncthreads();
        s[tid] += t;
        __syncthreads();
    }
    if (g < NN) part[g] = s[tid] - v;           // exclusive within block
    if (tid == 1023) bsum[blockIdx.x] = s[1023];
}

__global__ void k_scanB(int* __restrict__ bsum) {
    __shared__ int s[64];
    int tid = threadIdx.x;
    int v = (tid < NB) ? bsum[tid] : 0;
    s[tid] = v;
    __syncthreads();
    for (int ofs = 1; ofs < 64; ofs <<= 1) {
        int t = (tid >= ofs) ? s[tid - ofs] : 0;
        __syncthreads();
        s[tid] += t;
        __syncthreads();
    }
    if (tid < NB) bsum[tid] = s[tid] - v;       // exclusive
}

__global__ void k_scanC(const int* __restrict__ part, const int* __restrict__ bsum, int* __restrict__ cursor) {
    int g = blockIdx.x * 256 + threadIdx.x;
    if (g < NN) cursor[g] = part[g] + bsum[g >> 10];
}

__global__ void k_reorder(const int* __restrict__ from_idx, const int* __restrict__ to_idx,
                          int* __restrict__ cursor, int* __restrict__ sf, int* __restrict__ st) {
    int e = blockIdx.x * 256 + threadIdx.x;
    if (e < NE) {
        int d = to_idx[e];
        int p = atomicAdd(&cursor[d], 1);
        sf[p] = from_idx[e];
        st[p] = d;
    }
}

// ---------------- edge kernel v10: v8 + HAND-pipelined B-frags + hoisted biases ----------------
// v8 validated (244.8us): sorted edges + block segmented reduction. v9 showed the compiler won't
// software-pipeline on its own (VGPR stuck at 88). Here: explicit bA/bB double-buffer -- next
// nt's 8 B-frag loads issue before the current 16-MFMA burst -- plus all bias values hoisted to
// registers. Removes ~500cy of per-nt L2 wait from the ~800cy loop body.
__global__ __launch_bounds__(128, 2) void k_edges(
    const u16* __restrict__ nf16, const int* __restrict__ sf,
    const int* __restrict__ st, const u16* __restrict__ pW0,
    const float* __restrict__ b0, const u16* __restrict__ pW1,
    const float* __restrict__ b1, float* __restrict__ agg)
{
    __shared__ u16 sX[64 * XS];
    __shared__ int sDest[64];
    const int tid = threadIdx.x;
    const int lane = tid & 63;
    const int wave = tid >> 6;
    const int base = wave * 32;
    const int l15  = lane & 15;
    const int quad = lane >> 4;
    const int e0 = blockIdx.x * 64;

    if (tid < 64) sDest[tid] = st[e0 + tid];

    // hoist biases: 24 per-lane values into registers (static-indexed; issued before staging)
    float bias0[16], bias1[8];
    #pragma unroll
    for (int nt = 0; nt < 16; ++nt) bias0[nt] = b0[nt * 16 + l15];
    #pragma unroll
    for (int nt = 0; nt < 8; ++nt)  bias1[nt] = b1[nt * 16 + l15];

    // stage gather: 64 rows x 32 chunks of 8 bf16 (16 B); to-side rows repeat (sorted) -> cache-hot
    #pragma unroll
    for (int i = 0; i < 16; ++i) {
        int c = i * 128 + tid;
        int r = c >> 5, j = c & 31;
        int e = e0 + r;
        int node = (j < 16) ? sf[e] : st[e];
        *(u16x8*)(&sX[r * XS + j * 8]) = *(const u16x8*)(nf16 + node * DD + (j & 15) * 8);
    }
    __syncthreads();

    const int arow0 = (base + l15) * XS + quad * 8;

    // consume X fully into registers (A-frags), freeing sX rows for H (rows wave-private)
    bf16x8 a[2][8];
    #pragma unroll
    for (int mt = 0; mt < 2; ++mt)
        #pragma unroll
        for (int kt = 0; kt < 8; ++kt)
            a[mt][kt] = __builtin_bit_cast(bf16x8, *(const u16x8*)(&sX[arow0 + mt * 16 * XS + kt * 32]));

    // layer 0: H[64,256] = relu(X @ W0 + b0); explicit 2-deep B-frag pipeline
    bf16x8 bA[8], bB[8];
    loadB(bA, pW0, 0, lane);
    #pragma unroll
    for (int np = 0; np < 8; ++np) {
        const int ntA = 2 * np, ntB = 2 * np + 1;
        loadB(bB, pW0, ntB, lane);                    // in flight during bA burst
        f32x4 c0 = {0.f, 0.f, 0.f, 0.f}, c1 = {0.f, 0.f, 0.f, 0.f};
        #pragma unroll
        for (int kt = 0; kt < 8; ++kt) {
            c0 = __builtin_amdgcn_mfma_f32_16x16x32_bf16(a[0][kt], bA[kt], c0, 0, 0, 0);
            c1 = __builtin_amdgcn_mfma_f32_16x16x32_bf16(a[1][kt], bA[kt], c1, 0, 0, 0);
        }
        #pragma unroll
        for (int i = 0; i < 4; ++i) {
            sX[(base +      quad * 4 + i) * XS + ntA * 16 + l15] = f2bf(fmaxf(c0[i] + bias0[ntA], 0.f));
            sX[(base + 16 + quad * 4 + i) * XS + ntA * 16 + l15] = f2bf(fmaxf(c1[i] + bias0[ntA], 0.f));
        }
        if (np < 7) loadB(bA, pW0, ntA + 2, lane);    // in flight during bB burst
        f32x4 d0 = {0.f, 0.f, 0.f, 0.f}, d1 = {0.f, 0.f, 0.f, 0.f};
        #pragma unroll
        for (int kt = 0; kt < 8; ++kt) {
            d0 = __builtin_amdgcn_mfma_f32_16x16x32_bf16(a[0][kt], bB[kt], d0, 0, 0, 0);
            d1 = __builtin_amdgcn_mfma_f32_16x16x32_bf16(a[1][kt], bB[kt], d1, 0, 0, 0);
        }
        #pragma unroll
        for (int i = 0; i < 4; ++i) {
            sX[(base +      quad * 4 + i) * XS + ntB * 16 + l15] = f2bf(fmaxf(d0[i] + bias0[ntB], 0.f));
            sX[(base + 16 + quad * 4 + i) * XS + ntB * 16 + l15] = f2bf(fmaxf(d1[i] + bias0[ntB], 0.f));
        }
    }

    // layer 1 A-frags from H (same rows, in-wave ordered: no barrier needed)
    #pragma unroll
    for (int mt = 0; mt < 2; ++mt)
        #pragma unroll
        for (int kt = 0; kt < 8; ++kt)
            a[mt][kt] = __builtin_bit_cast(bf16x8, *(const u16x8*)(&sX[arow0 + mt * 16 * XS + kt * 32]));

    __syncthreads();   // fence: u16 H-reads above must complete before fp32 m-writes below (TBAA)

    // layer 1: m = relu(H @ W1 + b1) -> fp32 into sM (reuses sX bytes; rows wave-private)
    float* sM = (float*)sX;   // [64][132] fp32 view, 132*4 = 264*2 bytes ✓
    loadB(bA, pW1, 0, lane);
    #pragma unroll
    for (int np = 0; np < 4; ++np) {
        const int ntA = 2 * np, ntB = 2 * np + 1;
        loadB(bB, pW1, ntB, lane);
        f32x4 c0 = {0.f, 0.f, 0.f, 0.f}, c1 = {0.f, 0.f, 0.f, 0.f};
        #pragma unroll
        for (int kt = 0; kt < 8; ++kt) {
            c0 = __builtin_amdgcn_mfma_f32_16x16x32_bf16(a[0][kt], bA[kt], c0, 0, 0, 0);
            c1 = __builtin_amdgcn_mfma_f32_16x16x32_bf16(a[1][kt], bA[kt], c1, 0, 0, 0);
        }
        #pragma unroll
        for (int i = 0; i < 4; ++i) {
            sM[(base +      quad * 4 + i) * 132 + ntA * 16 + l15] = fmaxf(c0[i] + bias1[ntA], 0.f);
            sM[(base + 16 + quad * 4 + i) * 132 + ntA * 16 + l15] = fmaxf(c1[i] + bias1[ntA], 0.f);
        }
        if (np < 3) loadB(bA, pW1, ntA + 2, lane);
        f32x4 d0 = {0.f, 0.f, 0.f, 0.f}, d1 = {0.f, 0.f, 0.f, 0.f};
        #pragma unroll
        for (int kt = 0; kt < 8; ++kt) {
            d0 = __builtin_amdgcn_mfma_f32_16x16x32_bf16(a[0][kt], bB[kt], d0, 0, 0, 0);
            d1 = __builtin_amdgcn_mfma_f32_16x16x32_bf16(a[1][kt], bB[kt], d1, 0, 0, 0);
        }
        #pragma unroll
        for (int i = 0; i < 4; ++i) {
            sM[(base +      quad * 4 + i) * 132 + ntB * 16 + l15] = fmaxf(d0[i] + bias1[ntB], 0.f);
            sM[(base + 16 + quad * 4 + i) * 132 + ntB * 16 + l15] = fmaxf(d1[i] + bias1[ntB], 0.f);
        }
    }
    __syncthreads();

    // block-wide segmented reduction over 64 sorted rows; thread = column (128 cols)
    const int head_d = sDest[0];
    const int tail_d = sDest[63];
    const bool head_sh = (e0 > 0) && (st[e0 - 1] == head_d);
    const bool tail_sh = (e0 + 64 < NE) && (st[e0 + 64] == tail_d);

    int dprev = head_d;
    float acc = sM[tid];          // row 0
    for (int r = 1; r < 64; ++r) {
        int d = sDest[r];         // wave-uniform -> uniform branch
        float v = sM[r * 132 + tid];
        if (d == dprev) acc += v;
        else {
            if ((dprev == head_d && head_sh) || (dprev == tail_d && tail_sh))
                unsafeAtomicAdd(&agg[(size_t)dprev * DD + tid], acc);
            else
                agg[(size_t)dprev * DD + tid] = acc;   // sole writer (interior run)
            acc = v; dprev = d;
        }
    }
    if ((dprev == head_d && head_sh) || (dprev == tail_d && tail_sh))
        unsafeAtomicAdd(&agg[(size_t)dprev * DD + tid], acc);
    else
        agg[(size_t)dprev * DD + tid] = acc;
}

// Node update: r7-validated structure + same hand pipeline + bias hoist
__global__ __launch_bounds__(128, 2) void k_update(
    const float* __restrict__ agg, const u16* __restrict__ nf16,
    const float* __restrict__ nf32, const u16* __restrict__ pW0,
    const float* __restrict__ b0, const u16* __restrict__ pW1,
    const float* __restrict__ b1, float* __restrict__ out)
{
    __shared__ u16 sX[64 * XS];
    const int tid = threadIdx.x;
    const int lane = tid & 63;
    const int wave = tid >> 6;
    const int base = wave * 32;
    const int l15  = lane & 15;
    const int quad = lane >> 4;
    const int n0 = blockIdx.x * 64;

    float bias0[16], bias1[8];
    #pragma unroll
    for (int nt = 0; nt < 16; ++nt) bias0[nt] = b0[nt * 16 + l15];
    #pragma unroll
    for (int nt = 0; nt < 8; ++nt)  bias1[nt] = b1[nt * 16 + l15];

    // stage agg half (cols 0..127), fp32->bf16
    #pragma unroll
    for (int i = 0; i < 16; ++i) {
        int c = i * 128 + tid;
        int r = c >> 5, j = c & 31;
        int n = n0 + r;
        u16x4 o;
        if (n < NN) {
            float4 v = *(const float4*)(agg + (size_t)n * DD + j * 4);
            o[0] = f2bf(v.x); o[1] = f2bf(v.y); o[2] = f2bf(v.z); o[3] = f2bf(v.w);
        } else { o[0] = 0; o[1] = 0; o[2] = 0; o[3] = 0; }
        *(u16x4*)(&sX[r * XS + j * 4]) = o;
    }
    // stage nf half (cols 128..255), bf16 copy
    #pragma unroll
    for (int i = 0; i < 8; ++i) {
        int c = i * 128 + tid;
        int r = c >> 4, j = c & 15;
        int n = n0 + r;
        u16x8 v = {0, 0, 0, 0, 0, 0, 0, 0};
        if (n < NN) v = *(const u16x8*)(nf16 + (size_t)n * DD + j * 8);
        *(u16x8*)(&sX[r * XS + 128 + j * 8]) = v;
    }
    __syncthreads();

    const int arow0 = (base + l15) * XS + quad * 8;

    bf16x8 a[2][8];
    #pragma unroll
    for (int mt = 0; mt < 2; ++mt)
        #pragma unroll
        for (int kt = 0; kt < 8; ++kt)
            a[mt][kt] = __builtin_bit_cast(bf16x8, *(const u16x8*)(&sX[arow0 + mt * 16 * XS + kt * 32]));

    bf16x8 bA[8], bB[8];
    loadB(bA, pW0, 0, lane);
    #pragma unroll
    for (int np = 0; np < 8; ++np) {
        const int ntA = 2 * np, ntB = 2 * np + 1;
        loadB(bB, pW0, ntB, lane);
        f32x4 c0 = {0.f, 0.f, 0.f, 0.f}, c1 = {0.f, 0.f, 0.f, 0.f};
        #pragma unroll
        for (int kt = 0; kt < 8; ++kt) {
            c0 = __builtin_amdgcn_mfma_f32_16x16x32_bf16(a[0][kt], bA[kt], c0, 0, 0, 0);
            c1 = __builtin_amdgcn_mfma_f32_16x16x32_bf16(a[1][kt], bA[kt], c1, 0, 0, 0);
        }
        #pragma unroll
        for (int i = 0; i < 4; ++i) {
            sX[(base +      quad * 4 + i) * XS + ntA * 16 + l15] = f2bf(fmaxf(c0[i] + bias0[ntA], 0.f));
            sX[(base + 16 + quad * 4 + i) * XS + ntA * 16 + l15] = f2bf(fmaxf(c1[i] + bias0[ntA], 0.f));
        }
        if (np < 7) loadB(bA, pW0, ntA + 2, lane);
        f32x4 d0 = {0.f, 0.f, 0.f, 0.f}, d1 = {0.f, 0.f, 0.f, 0.f};
        #pragma unroll
        for (int kt = 0; kt < 8; ++kt) {
            d0 = __builtin_amdgcn_mfma_f32_16x16x32_bf16(a[0][kt], bB[kt], d0, 0, 0, 0);
            d1 = __builtin_amdgcn_mfma_f32_16x16x32_bf16(a[1][kt], bB[kt], d1, 0, 0, 0);
        }
        #pragma unroll
        for (int i = 0; i < 4; ++i) {
            sX[(base +      quad * 4 + i) * XS + ntB * 16 + l15] = f2bf(fmaxf(d0[i] + bias0[ntB], 0.f));
            sX[(base + 16 + quad * 4 + i) * XS + ntB * 16 + l15] = f2bf(fmaxf(d1[i] + bias0[ntB], 0.f));
        }
    }

    #pragma unroll
    for (int mt = 0; mt < 2; ++mt)
        #pragma unroll
        for (int kt = 0; kt < 8; ++kt)
            a[mt][kt] = __builtin_bit_cast(bf16x8, *(const u16x8*)(&sX[arow0 + mt * 16 * XS + kt * 32]));

    loadB(bA, pW1, 0, lane);
    #pragma unroll
    for (int np = 0; np < 4; ++np) {
        const int ntA = 2 * np, ntB = 2 * np + 1;
        loadB(bB, pW1, ntB, lane);
        f32x4 c0 = {0.f, 0.f, 0.f, 0.f}, c1 = {0.f, 0.f, 0.f, 0.f};
        #pragma unroll
        for (int kt = 0; kt < 8; ++kt) {
            c0 = __builtin_amdgcn_mfma_f32_16x16x32_bf16(a[0][kt], bA[kt], c0, 0, 0, 0);
            c1 = __builtin_amdgcn_mfma_f32_16x16x32_bf16(a[1][kt], bA[kt], c1, 0, 0, 0);
        }
        {
            int col = ntA * 16 + l15;
            #pragma unroll
            for (int i = 0; i < 4; ++i) {
                int na = n0 + base +      quad * 4 + i;
                int nb = n0 + base + 16 + quad * 4 + i;
                if (na < NN) out[(size_t)na * DD + col] = nf32[(size_t)na * DD + col] + fmaxf(c0[i] + bias1[ntA], 0.f);
                if (nb < NN) out[(size_t)nb * DD + col] = nf32[(size_t)nb * DD + col] + fmaxf(c1[i] + bias1[ntA], 0.f);
            }
        }
        if (np < 3) loadB(bA, pW1, ntA + 2, lane);
        f32x4 d0 = {0.f, 0.f, 0.f, 0.f}, d1 = {0.f, 0.f, 0.f, 0.f};
        #pragma unroll
        for (int kt = 0; kt < 8; ++kt) {
            d0 = __builtin_amdgcn_mfma_f32_16x16x32_bf16(a[0][kt], bB[kt], d0, 0, 0, 0);
            d1 = __builtin_amdgcn_mfma_f32_16x16x32_bf16(a[1][kt], bB[kt], d1, 0, 0, 0);
        }
        {
            int col = ntB * 16 + l15;
            #pragma unroll
            for (int i = 0; i < 4; ++i) {
                int na = n0 + base +      quad * 4 + i;
                int nb = n0 + base + 16 + quad * 4 + i;
                if (na < NN) out[(size_t)na * DD + col] = nf32[(size_t)na * DD + col] + fmaxf(d0[i] + bias1[ntB], 0.f);
                if (nb < NN) out[(size_t)nb * DD + col] = nf32[(size_t)nb * DD + col] + fmaxf(d1[i] + bias1[ntB], 0.f);
            }
        }
    }
}

extern "C" void kernel_launch(void* const* d_in, const int* in_sizes, int n_in,
                              void* d_out, int out_size, void* d_ws, size_t ws_size,
                              hipStream_t stream)
{
    const float* nf  = (const float*)d_in[0];
    const int* fidx  = (const int*)d_in[1];
    const int* tidx  = (const int*)d_in[2];
    const float* mW0 = (const float*)d_in[3];
    const float* mb0 = (const float*)d_in[4];
    const float* mW1 = (const float*)d_in[5];
    const float* mb1 = (const float*)d_in[6];
    const float* uW0 = (const float*)d_in[7];
    const float* ub0 = (const float*)d_in[8];
    const float* uW1 = (const float*)d_in[9];
    const float* ub1 = (const float*)d_in[10];
    float* out = (float*)d_out;

    char* ws = (char*)d_ws;
    u16*   nf16 = (u16*)ws;   ws += (size_t)NN * DD * 2;   // 12.8 MB
    float* agg  = (float*)ws; ws += (size_t)NN * DD * 4;   // 25.6 MB
    u16*   pmW0 = (u16*)ws;   ws += 256 * 256 * 2;
    u16*   pmW1 = (u16*)ws;   ws += 256 * 128 * 2;
    u16*   puW0 = (u16*)ws;   ws += 256 * 256 * 2;
    u16*   puW1 = (u16*)ws;   ws += 256 * 128 * 2;
    int*   cnt    = (int*)ws; ws += (size_t)NN * 4;        // 0.2 MB
    int*   cursor = (int*)ws; ws += (size_t)NN * 4;        // 0.2 MB
    int*   part   = (int*)ws; ws += (size_t)NN * 4;        // 0.2 MB
    int*   bsum   = (int*)ws; ws += 64 * 4;
    int*   sf     = (int*)ws; ws += (size_t)NE * 4;        // 2.4 MB
    int*   st     = (int*)ws; ws += (size_t)NE * 4;        // 2.4 MB

    hipMemsetAsync(agg, 0, (size_t)NN * DD * 4, stream);
    hipMemsetAsync(cnt, 0, (size_t)NN * 4, stream);
    k_convert_nf<<<(NN * DD / 4) / 256, 256, 0, stream>>>(nf, nf16);
    k_pack<<<256, 256, 0, stream>>>(mW0, pmW0, 256, 256);
    k_pack<<<128, 256, 0, stream>>>(mW1, pmW1, 256, 128);
    k_pack<<<256, 256, 0, stream>>>(uW0, puW0, 256, 256);
    k_pack<<<128, 256, 0, stream>>>(uW1, puW1, 256, 128);
    k_hist<<<(NE + 255) / 256, 256, 0, stream>>>(tidx, cnt);
    k_scanA<<<NB, 1024, 0, stream>>>(cnt, part, bsum);
    k_scanB<<<1, 64, 0, stream>>>(bsum);
    k_scanC<<<(NN + 255) / 256, 256, 0, stream>>>(part, bsum, cursor);
    k_reorder<<<(NE + 255) / 256, 256, 0, stream>>>(fidx, tidx, cursor, sf, st);
    k_edges<<<NE / 64, 128, 0, stream>>>(nf16, sf, st, pmW0, mb0, pmW1, mb1, agg);
    k_update<<<(NN + 63) / 64, 128, 0, stream>>>(agg, nf16, nf, puW0, ub0, puW1, ub1, out);
}

// Round 13
// 370.592 us; speedup vs baseline: 1.2821x; 1.0442x over previous
//
#include <hip/hip_runtime.h>

#define NN 50000
#define NE 600000
#define DD 128
#define XS 264   // padded LDS row stride in bf16 elems: 528 B = 132 fp32 (exact fp32 reuse for m-buffer)
#define NB 49    // scan blocks: ceil(NN/1024)

typedef unsigned short u16;
typedef u16   u16x8  __attribute__((ext_vector_type(8)));
typedef u16   u16x4  __attribute__((ext_vector_type(4)));
typedef __bf16 bf16x8 __attribute__((ext_vector_type(8)));
typedef float f32x4  __attribute__((ext_vector_type(4)));

__device__ __forceinline__ u16 f2bf(float f) {  // RNE fp32->bf16
    unsigned u = __builtin_bit_cast(unsigned, f);
    u += 0x7FFFu + ((u >> 16) & 1u);
    return (u16)(u >> 16);
}

// load one nt-column of packed W into 8 named B-frag registers
__device__ __forceinline__ void loadB(bf16x8 (&d)[8], const u16* __restrict__ pw, int nt, int lane) {
    #pragma unroll
    for (int kt = 0; kt < 8; ++kt)
        d[kt] = __builtin_bit_cast(bf16x8, *(const u16x8*)(pw + (nt * 8 + kt) * 512 + lane * 8));
}

// node_features fp32 [NN,DD] -> bf16 table
__global__ void k_convert_nf(const float* __restrict__ nf, u16* __restrict__ out) {
    int id = blockIdx.x * 256 + threadIdx.x;            // NN*DD/4 threads exactly
    float4 v = ((const float4*)nf)[id];
    u16x4 o; o[0] = f2bf(v.x); o[1] = f2bf(v.y); o[2] = f2bf(v.z); o[3] = f2bf(v.w);
    ((u16x4*)out)[id] = o;
}

// Pack W[K,N] fp32 row-major into MFMA B-fragment order for 16x16x32
__global__ void k_pack(const float* __restrict__ W, u16* __restrict__ out, int K, int N) {
    int tid = blockIdx.x * 256 + threadIdx.x;
    if (tid >= K * N) return;
    int frag = tid >> 9, lane = (tid >> 3) & 63, j = tid & 7;
    int KT = K >> 5;
    int nt = frag / KT, kt = frag - nt * KT;
    int row = kt * 32 + ((lane >> 4) << 3) + j;
    int col = nt * 16 + (lane & 15);
    out[tid] = f2bf(W[row * N + col]);
}

// ---------------- counting sort of edges by destination (multi-block scan; validated r7) ----------------
__global__ void k_hist(const int* __restrict__ to_idx, int* __restrict__ cnt) {
    int e = blockIdx.x * 256 + threadIdx.x;
    if (e < NE) atomicAdd(&cnt[to_idx[e]], 1);
}

__global__ void k_scanA(const int* __restrict__ cnt, int* __restrict__ part, int* __restrict__ bsum) {
    __shared__ int s[1024];
    int tid = threadIdx.x;
    int g = blockIdx.x * 1024 + tid;
    int v = (g < NN) ? cnt[g] : 0;
    s[tid] = v;
    __syncthreads();
    for (int ofs = 1; ofs < 1024; ofs <<= 1) {
        int t = (tid >= ofs) ? s[tid - ofs] : 0;
        __syncthreads();
        s[tid] += t;
        __syncthreads();
    }
    if (g < NN) part[g] = s[tid] - v;           // exclusive within block
    if (tid == 1023) bsum[blockIdx.x] = s[1023];
}

__global__ void k_scanB(int* __restrict__ bsum) {
    __shared__ int s[64];
    int tid = threadIdx.x;
    int v = (tid < NB) ? bsum[tid] : 0;
    s[tid] = v;
    __syncthreads();
    for (int ofs = 1; ofs < 64; ofs <<= 1) {
        int t = (tid >= ofs) ? s[tid - ofs] : 0;
        __syncthreads();
        s[tid] += t;
        __syncthreads();
    }
    if (tid < NB) bsum[tid] = s[tid] - v;       // exclusive
}

__global__ void k_scanC(const int* __restrict__ part, const int* __restrict__ bsum, int* __restrict__ cursor) {
    int g = blockIdx.x * 256 + threadIdx.x;
    if (g < NN) cursor[g] = part[g] + bsum[g >> 10];
}

__global__ void k_reorder(const int* __restrict__ from_idx, const int* __restrict__ to_idx,
                          int* __restrict__ cursor, int* __restrict__ sf, int* __restrict__ st) {
    int e = blockIdx.x * 256 + threadIdx.x;
    if (e < NE) {
        int d = to_idx[e];
        int p = atomicAdd(&cursor[d], 1);
        sf[p] = from_idx[e];
        st[p] = d;
    }
}

// ---------------- edge kernel v11: v10 + sched_barrier-pinned B-frag double-buffer ----------------
// v10's VGPR=88 proved regalloc coalesced bA/bB (pipeline never materialized; gain was bias
// hoist). sched_barrier(0) after each prefetch pins the loads above the other buffer's MFMA
// burst -> live ranges overlap -> both buffers allocated -> vmcnt wait covered by ~400cy of
// burst+epilogue. (Rule #18 pattern, m214.)
__global__ __launch_bounds__(128, 2) void k_edges(
    const u16* __restrict__ nf16, const int* __restrict__ sf,
    const int* __restrict__ st, const u16* __restrict__ pW0,
    const float* __restrict__ b0, const u16* __restrict__ pW1,
    const float* __restrict__ b1, float* __restrict__ agg)
{
    __shared__ u16 sX[64 * XS];
    __shared__ int sDest[64];
    const int tid = threadIdx.x;
    const int lane = tid & 63;
    const int wave = tid >> 6;
    const int base = wave * 32;
    const int l15  = lane & 15;
    const int quad = lane >> 4;
    const int e0 = blockIdx.x * 64;

    if (tid < 64) sDest[tid] = st[e0 + tid];

    // hoist biases: 24 per-lane values into registers (validated v10 win)
    float bias0[16], bias1[8];
    #pragma unroll
    for (int nt = 0; nt < 16; ++nt) bias0[nt] = b0[nt * 16 + l15];
    #pragma unroll
    for (int nt = 0; nt < 8; ++nt)  bias1[nt] = b1[nt * 16 + l15];

    // stage gather: 64 rows x 32 chunks of 8 bf16 (16 B); to-side rows repeat (sorted) -> cache-hot
    #pragma unroll
    for (int i = 0; i < 16; ++i) {
        int c = i * 128 + tid;
        int r = c >> 5, j = c & 31;
        int e = e0 + r;
        int node = (j < 16) ? sf[e] : st[e];
        *(u16x8*)(&sX[r * XS + j * 8]) = *(const u16x8*)(nf16 + node * DD + (j & 15) * 8);
    }
    __syncthreads();

    const int arow0 = (base + l15) * XS + quad * 8;

    // consume X fully into registers (A-frags), freeing sX rows for H (rows wave-private)
    bf16x8 a[2][8];
    #pragma unroll
    for (int mt = 0; mt < 2; ++mt)
        #pragma unroll
        for (int kt = 0; kt < 8; ++kt)
            a[mt][kt] = __builtin_bit_cast(bf16x8, *(const u16x8*)(&sX[arow0 + mt * 16 * XS + kt * 32]));

    // layer 0: H[64,256] = relu(X @ W0 + b0); pinned 2-deep B-frag pipeline
    bf16x8 bA[8], bB[8];
    loadB(bA, pW0, 0, lane);
    #pragma unroll
    for (int np = 0; np < 8; ++np) {
        const int ntA = 2 * np, ntB = 2 * np + 1;
        loadB(bB, pW0, ntB, lane);                    // issue now...
        __builtin_amdgcn_sched_barrier(0);            // ...and stay issued (no sinking past here)
        f32x4 c0 = {0.f, 0.f, 0.f, 0.f}, c1 = {0.f, 0.f, 0.f, 0.f};
        #pragma unroll
        for (int kt = 0; kt < 8; ++kt) {
            c0 = __builtin_amdgcn_mfma_f32_16x16x32_bf16(a[0][kt], bA[kt], c0, 0, 0, 0);
            c1 = __builtin_amdgcn_mfma_f32_16x16x32_bf16(a[1][kt], bA[kt], c1, 0, 0, 0);
        }
        #pragma unroll
        for (int i = 0; i < 4; ++i) {
            sX[(base +      quad * 4 + i) * XS + ntA * 16 + l15] = f2bf(fmaxf(c0[i] + bias0[ntA], 0.f));
            sX[(base + 16 + quad * 4 + i) * XS + ntA * 16 + l15] = f2bf(fmaxf(c1[i] + bias0[ntA], 0.f));
        }
        if (np < 7) {
            loadB(bA, pW0, ntA + 2, lane);
            __builtin_amdgcn_sched_barrier(0);
        }
        f32x4 d0 = {0.f, 0.f, 0.f, 0.f}, d1 = {0.f, 0.f, 0.f, 0.f};
        #pragma unroll
        for (int kt = 0; kt < 8; ++kt) {
            d0 = __builtin_amdgcn_mfma_f32_16x16x32_bf16(a[0][kt], bB[kt], d0, 0, 0, 0);
            d1 = __builtin_amdgcn_mfma_f32_16x16x32_bf16(a[1][kt], bB[kt], d1, 0, 0, 0);
        }
        #pragma unroll
        for (int i = 0; i < 4; ++i) {
            sX[(base +      quad * 4 + i) * XS + ntB * 16 + l15] = f2bf(fmaxf(d0[i] + bias0[ntB], 0.f));
            sX[(base + 16 + quad * 4 + i) * XS + ntB * 16 + l15] = f2bf(fmaxf(d1[i] + bias0[ntB], 0.f));
        }
    }

    // layer 1 A-frags from H (same rows, in-wave ordered: no barrier needed)
    #pragma unroll
    for (int mt = 0; mt < 2; ++mt)
        #pragma unroll
        for (int kt = 0; kt < 8; ++kt)
            a[mt][kt] = __builtin_bit_cast(bf16x8, *(const u16x8*)(&sX[arow0 + mt * 16 * XS + kt * 32]));

    __syncthreads();   // fence: u16 H-reads above must complete before fp32 m-writes below (TBAA)

    // layer 1: m = relu(H @ W1 + b1) -> fp32 into sM (reuses sX bytes; rows wave-private)
    float* sM = (float*)sX;   // [64][132] fp32 view, 132*4 = 264*2 bytes ✓
    loadB(bA, pW1, 0, lane);
    #pragma unroll
    for (int np = 0; np < 4; ++np) {
        const int ntA = 2 * np, ntB = 2 * np + 1;
        loadB(bB, pW1, ntB, lane);
        __builtin_amdgcn_sched_barrier(0);
        f32x4 c0 = {0.f, 0.f, 0.f, 0.f}, c1 = {0.f, 0.f, 0.f, 0.f};
        #pragma unroll
        for (int kt = 0; kt < 8; ++kt) {
            c0 = __builtin_amdgcn_mfma_f32_16x16x32_bf16(a[0][kt], bA[kt], c0, 0, 0, 0);
            c1 = __builtin_amdgcn_mfma_f32_16x16x32_bf16(a[1][kt], bA[kt], c1, 0, 0, 0);
        }
        #pragma unroll
        for (int i = 0; i < 4; ++i) {
            sM[(base +      quad * 4 + i) * 132 + ntA * 16 + l15] = fmaxf(c0[i] + bias1[ntA], 0.f);
            sM[(base + 16 + quad * 4 + i) * 132 + ntA * 16 + l15] = fmaxf(c1[i] + bias1[ntA], 0.f);
        }
        if (np < 3) {
            loadB(bA, pW1, ntA + 2, lane);
            __builtin_amdgcn_sched_barrier(0);
        }
        f32x4 d0 = {0.f, 0.f, 0.f, 0.f}, d1 = {0.f, 0.f, 0.f, 0.f};
        #pragma unroll
        for (int kt = 0; kt < 8; ++kt) {
            d0 = __builtin_amdgcn_mfma_f32_16x16x32_bf16(a[0][kt], bB[kt], d0, 0, 0, 0);
            d1 = __builtin_amdgcn_mfma_f32_16x16x32_bf16(a[1][kt], bB[kt], d1, 0, 0, 0);
        }
        #pragma unroll
        for (int i = 0; i < 4; ++i) {
            sM[(base +      quad * 4 + i) * 132 + ntB * 16 + l15] = fmaxf(d0[i] + bias1[ntB], 0.f);
            sM[(base + 16 + quad * 4 + i) * 132 + ntB * 16 + l15] = fmaxf(d1[i] + bias1[ntB], 0.f);
        }
    }
    __syncthreads();

    // block-wide segmented reduction over 64 sorted rows; thread = column (128 cols)
    const int head_d = sDest[0];
    const int tail_d = sDest[63];
    const bool head_sh = (e0 > 0) && (st[e0 - 1] == head_d);
    const bool tail_sh = (e0 + 64 < NE) && (st[e0 + 64] == tail_d);

    int dprev = head_d;
    float acc = sM[tid];          // row 0
    for (int r = 1; r < 64; ++r) {
        int d = sDest[r];         // wave-uniform -> uniform branch
        float v = sM[r * 132 + tid];
        if (d == dprev) acc += v;
        else {
            if ((dprev == head_d && head_sh) || (dprev == tail_d && tail_sh))
                unsafeAtomicAdd(&agg[(size_t)dprev * DD + tid], acc);
            else
                agg[(size_t)dprev * DD + tid] = acc;   // sole writer (interior run)
            acc = v; dprev = d;
        }
    }
    if ((dprev == head_d && head_sh) || (dprev == tail_d && tail_sh))
        unsafeAtomicAdd(&agg[(size_t)dprev * DD + tid], acc);
    else
        agg[(size_t)dprev * DD + tid] = acc;
}

// Node update: v10 structure + same pinned pipeline
__global__ __launch_bounds__(128, 2) void k_update(
    const float* __restrict__ agg, const u16* __restrict__ nf16,
    const float* __restrict__ nf32, const u16* __restrict__ pW0,
    const float* __restrict__ b0, const u16* __restrict__ pW1,
    const float* __restrict__ b1, float* __restrict__ out)
{
    __shared__ u16 sX[64 * XS];
    const int tid = threadIdx.x;
    const int lane = tid & 63;
    const int wave = tid >> 6;
    const int base = wave * 32;
    const int l15  = lane & 15;
    const int quad = lane >> 4;
    const int n0 = blockIdx.x * 64;

    float bias0[16], bias1[8];
    #pragma unroll
    for (int nt = 0; nt < 16; ++nt) bias0[nt] = b0[nt * 16 + l15];
    #pragma unroll
    for (int nt = 0; nt < 8; ++nt)  bias1[nt] = b1[nt * 16 + l15];

    // stage agg half (cols 0..127), fp32->bf16
    #pragma unroll
    for (int i = 0; i < 16; ++i) {
        int c = i * 128 + tid;
        int r = c >> 5, j = c & 31;
        int n = n0 + r;
        u16x4 o;
        if (n < NN) {
            float4 v = *(const float4*)(agg + (size_t)n * DD + j * 4);
            o[0] = f2bf(v.x); o[1] = f2bf(v.y); o[2] = f2bf(v.z); o[3] = f2bf(v.w);
        } else { o[0] = 0; o[1] = 0; o[2] = 0; o[3] = 0; }
        *(u16x4*)(&sX[r * XS + j * 4]) = o;
    }
    // stage nf half (cols 128..255), bf16 copy
    #pragma unroll
    for (int i = 0; i < 8; ++i) {
        int c = i * 128 + tid;
        int r = c >> 4, j = c & 15;
        int n = n0 + r;
        u16x8 v = {0, 0, 0, 0, 0, 0, 0, 0};
        if (n < NN) v = *(const u16x8*)(nf16 + (size_t)n * DD + j * 8);
        *(u16x8*)(&sX[r * XS + 128 + j * 8]) = v;
    }
    __syncthreads();

    const int arow0 = (base + l15) * XS + quad * 8;

    bf16x8 a[2][8];
    #pragma unroll
    for (int mt = 0; mt < 2; ++mt)
        #pragma unroll
        for (int kt = 0; kt < 8; ++kt)
            a[mt][kt] = __builtin_bit_cast(bf16x8, *(const u16x8*)(&sX[arow0 + mt * 16 * XS + kt * 32]));

    bf16x8 bA[8], bB[8];
    loadB(bA, pW0, 0, lane);
    #pragma unroll
    for (int np = 0; np < 8; ++np) {
        const int ntA = 2 * np, ntB = 2 * np + 1;
        loadB(bB, pW0, ntB, lane);
        __builtin_amdgcn_sched_barrier(0);
        f32x4 c0 = {0.f, 0.f, 0.f, 0.f}, c1 = {0.f, 0.f, 0.f, 0.f};
        #pragma unroll
        for (int kt = 0; kt < 8; ++kt) {
            c0 = __builtin_amdgcn_mfma_f32_16x16x32_bf16(a[0][kt], bA[kt], c0, 0, 0, 0);
            c1 = __builtin_amdgcn_mfma_f32_16x16x32_bf16(a[1][kt], bA[kt], c1, 0, 0, 0);
        }
        #pragma unroll
        for (int i = 0; i < 4; ++i) {
            sX[(base +      quad * 4 + i) * XS + ntA * 16 + l15] = f2bf(fmaxf(c0[i] + bias0[ntA], 0.f));
            sX[(base + 16 + quad * 4 + i) * XS + ntA * 16 + l15] = f2bf(fmaxf(c1[i] + bias0[ntA], 0.f));
        }
        if (np < 7) {
            loadB(bA, pW0, ntA + 2, lane);
            __builtin_amdgcn_sched_barrier(0);
        }
        f32x4 d0 = {0.f, 0.f, 0.f, 0.f}, d1 = {0.f, 0.f, 0.f, 0.f};
        #pragma unroll
        for (int kt = 0; kt < 8; ++kt) {
            d0 = __builtin_amdgcn_mfma_f32_16x16x32_bf16(a[0][kt], bB[kt], d0, 0, 0, 0);
            d1 = __builtin_amdgcn_mfma_f32_16x16x32_bf16(a[1][kt], bB[kt], d1, 0, 0, 0);
        }
        #pragma unroll
        for (int i = 0; i < 4; ++i) {
            sX[(base +      quad * 4 + i) * XS + ntB * 16 + l15] = f2bf(fmaxf(d0[i] + bias0[ntB], 0.f));
            sX[(base + 16 + quad * 4 + i) * XS + ntB * 16 + l15] = f2bf(fmaxf(d1[i] + bias0[ntB], 0.f));
        }
    }

    #pragma unroll
    for (int mt = 0; mt < 2; ++mt)
        #pragma unroll
        for (int kt = 0; kt < 8; ++kt)
            a[mt][kt] = __builtin_bit_cast(bf16x8, *(const u16x8*)(&sX[arow0 + mt * 16 * XS + kt * 32]));

    loadB(bA, pW1, 0, lane);
    #pragma unroll
    for (int np = 0; np < 4; ++np) {
        const int ntA = 2 * np, ntB = 2 * np + 1;
        loadB(bB, pW1, ntB, lane);
        __builtin_amdgcn_sched_barrier(0);
        f32x4 c0 = {0.f, 0.f, 0.f, 0.f}, c1 = {0.f, 0.f, 0.f, 0.f};
        #pragma unroll
        for (int kt = 0; kt < 8; ++kt) {
            c0 = __builtin_amdgcn_mfma_f32_16x16x32_bf16(a[0][kt], bA[kt], c0, 0, 0, 0);
            c1 = __builtin_amdgcn_mfma_f32_16x16x32_bf16(a[1][kt], bA[kt], c1, 0, 0, 0);
        }
        {
            int col = ntA * 16 + l15;
            #pragma unroll
            for (int i = 0; i < 4; ++i) {
                int na = n0 + base +      quad * 4 + i;
                int nb = n0 + base + 16 + quad * 4 + i;
                if (na < NN) out[(size_t)na * DD + col] = nf32[(size_t)na * DD + col] + fmaxf(c0[i] + bias1[ntA], 0.f);
                if (nb < NN) out[(size_t)nb * DD + col] = nf32[(size_t)nb * DD + col] + fmaxf(c1[i] + bias1[ntA], 0.f);
            }
        }
        if (np < 3) {
            loadB(bA, pW1, ntA + 2, lane);
            __builtin_amdgcn_sched_barrier(0);
        }
        f32x4 d0 = {0.f, 0.f, 0.f, 0.f}, d1 = {0.f, 0.f, 0.f, 0.f};
        #pragma unroll
        for (int kt = 0; kt < 8; ++kt) {
            d0 = __builtin_amdgcn_mfma_f32_16x16x32_bf16(a[0][kt], bB[kt], d0, 0, 0, 0);
            d1 = __builtin_amdgcn_mfma_f32_16x16x32_bf16(a[1][kt], bB[kt], d1, 0, 0, 0);
        }
        {
            int col = ntB * 16 + l15;
            #pragma unroll
            for (int i = 0; i < 4; ++i) {
                int na = n0 + base +      quad * 4 + i;
                int nb = n0 + base + 16 + quad * 4 + i;
                if (na < NN) out[(size_t)na * DD + col] = nf32[(size_t)na * DD + col] + fmaxf(d0[i] + bias1[ntB], 0.f);
                if (nb < NN) out[(size_t)nb * DD + col] = nf32[(size_t)nb * DD + col] + fmaxf(d1[i] + bias1[ntB], 0.f);
            }
        }
    }
}

extern "C" void kernel_launch(void* const* d_in, const int* in_sizes, int n_in,
                              void* d_out, int out_size, void* d_ws, size_t ws_size,
                              hipStream_t stream)
{
    const float* nf  = (const float*)d_in[0];
    const int* fidx  = (const int*)d_in[1];
    const int* tidx  = (const int*)d_in[2];
    const float* mW0 = (const float*)d_in[3];
    const float* mb0 = (const float*)d_in[4];
    const float* mW1 = (const float*)d_in[5];
    const float* mb1 = (const float*)d_in[6];
    const float* uW0 = (const float*)d_in[7];
    const float* ub0 = (const float*)d_in[8];
    const float* uW1 = (const float*)d_in[9];
    const float* ub1 = (const float*)d_in[10];
    float* out = (float*)d_out;

    char* ws = (char*)d_ws;
    u16*   nf16 = (u16*)ws;   ws += (size_t)NN * DD * 2;   // 12.8 MB
    float* agg  = (float*)ws; ws += (size_t)NN * DD * 4;   // 25.6 MB
    u16*   pmW0 = (u16*)ws;   ws += 256 * 256 * 2;
    u16*   pmW1 = (u16*)ws;   ws += 256 * 128 * 2;
    u16*   puW0 = (u16*)ws;   ws += 256 * 256 * 2;
    u16*   puW1 = (u16*)ws;   ws += 256 * 128 * 2;
    int*   cnt    = (int*)ws; ws += (size_t)NN * 4;        // 0.2 MB
    int*   cursor = (int*)ws; ws += (size_t)NN * 4;        // 0.2 MB
    int*   part   = (int*)ws; ws += (size_t)NN * 4;        // 0.2 MB
    int*   bsum   = (int*)ws; ws += 64 * 4;
    int*   sf     = (int*)ws; ws += (size_t)NE * 4;        // 2.4 MB
    int*   st     = (int*)ws; ws += (size_t)NE * 4;        // 2.4 MB

    hipMemsetAsync(agg, 0, (size_t)NN * DD * 4, stream);
    hipMemsetAsync(cnt, 0, (size_t)NN * 4, stream);
    k_convert_nf<<<(NN * DD / 4) / 256, 256, 0, stream>>>(nf, nf16);
    k_pack<<<256, 256, 0, stream>>>(mW0, pmW0, 256, 256);
    k_pack<<<128, 256, 0, stream>>>(mW1, pmW1, 256, 128);
    k_pack<<<256, 256, 0, stream>>>(uW0, puW0, 256, 256);
    k_pack<<<128, 256, 0, stream>>>(uW1, puW1, 256, 128);
    k_hist<<<(NE + 255) / 256, 256, 0, stream>>>(tidx, cnt);
    k_scanA<<<NB, 1024, 0, stream>>>(cnt, part, bsum);
    k_scanB<<<1, 64, 0, stream>>>(bsum);
    k_scanC<<<(NN + 255) / 256, 256, 0, stream>>>(part, bsum, cursor);
    k_reorder<<<(NE + 255) / 256, 256, 0, stream>>>(fidx, tidx, cursor, sf, st);
    k_edges<<<NE / 64, 128, 0, stream>>>(nf16, sf, st, pmW0, mb0, pmW1, mb1, agg);
    k_update<<<(NN + 63) / 64, 128, 0, stream>>>(agg, nf16, nf, puW0, ub0, puW1, ub1, out);
}

// Round 14
// 360.267 us; speedup vs baseline: 1.3189x; 1.0287x over previous
//
#include <hip/hip_runtime.h>

#define NN 50000
#define NE 600000
#define DD 128
#define XS 264   // padded LDS row stride in bf16 elems: 528 B = 132 fp32 (exact fp32 reuse for m-buffer)
#define NB 49    // scan blocks: ceil(NN/1024)

typedef unsigned short u16;
typedef u16   u16x8  __attribute__((ext_vector_type(8)));
typedef u16   u16x4  __attribute__((ext_vector_type(4)));
typedef __bf16 bf16x8 __attribute__((ext_vector_type(8)));
typedef float f32x4  __attribute__((ext_vector_type(4)));

__device__ __forceinline__ u16 f2bf(float f) {  // RNE fp32->bf16
    unsigned u = __builtin_bit_cast(unsigned, f);
    u += 0x7FFFu + ((u >> 16) & 1u);
    return (u16)(u >> 16);
}

// load one nt-column of packed W into 8 named B-frag registers
__device__ __forceinline__ void loadB(bf16x8 (&d)[8], const u16* __restrict__ pw, int nt, int lane) {
    #pragma unroll
    for (int kt = 0; kt < 8; ++kt)
        d[kt] = __builtin_bit_cast(bf16x8, *(const u16x8*)(pw + (nt * 8 + kt) * 512 + lane * 8));
}

// pack one element of W[K,N] into MFMA B-fragment order (validated k_pack body)
__device__ __forceinline__ void pack_one(const float* __restrict__ W, u16* __restrict__ out,
                                         int K, int N, int tid) {
    int frag = tid >> 9, lane = (tid >> 3) & 63, j = tid & 7;
    int KT = K >> 5;
    int nt = frag / KT, kt = frag - nt * KT;
    int row = kt * 32 + ((lane >> 4) << 3) + j;
    int col = nt * 16 + (lane & 15);
    out[tid] = f2bf(W[row * N + col]);
}

// ---------------- fused prep: convert_nf + hist + 4x pack in one dispatch ----------------
// block ranges (uniform branch per block): [0,6250) convert, [6250,8594) hist, [8594,9362) packs
__global__ void k_prep(const float* __restrict__ nf, u16* __restrict__ nf16,
                       const int* __restrict__ to_idx, int* __restrict__ cnt,
                       const float* __restrict__ mW0, u16* __restrict__ pmW0,
                       const float* __restrict__ mW1, u16* __restrict__ pmW1,
                       const float* __restrict__ uW0, u16* __restrict__ puW0,
                       const float* __restrict__ uW1, u16* __restrict__ puW1)
{
    const int b = blockIdx.x;
    const int tid = threadIdx.x;
    if (b < 6250) {                      // convert: NN*DD/4 = 1.6M float4 lanes
        int id = b * 256 + tid;
        float4 v = ((const float4*)nf)[id];
        u16x4 o; o[0] = f2bf(v.x); o[1] = f2bf(v.y); o[2] = f2bf(v.z); o[3] = f2bf(v.w);
        ((u16x4*)nf16)[id] = o;
    } else if (b < 6250 + 2344) {        // hist
        int e = (b - 6250) * 256 + tid;
        if (e < NE) atomicAdd(&cnt[to_idx[e]], 1);
    } else {                             // packs: g in [0, 196608)
        int g = (b - 8594) * 256 + tid;
        if (g < 65536)       pack_one(mW0, pmW0, 256, 256, g);
        else if (g < 98304)  pack_one(mW1, pmW1, 256, 128, g - 65536);
        else if (g < 163840) pack_one(uW0, puW0, 256, 256, g - 98304);
        else                 pack_one(uW1, puW1, 256, 128, g - 163840);
    }
}

// ---------------- counting-sort scan stages (validated r7) ----------------
__global__ void k_scanA(const int* __restrict__ cnt, int* __restrict__ part, int* __restrict__ bsum) {
    __shared__ int s[1024];
    int tid = threadIdx.x;
    int g = blockIdx.x * 1024 + tid;
    int v = (g < NN) ? cnt[g] : 0;
    s[tid] = v;
    __syncthreads();
    for (int ofs = 1; ofs < 1024; ofs <<= 1) {
        int t = (tid >= ofs) ? s[tid - ofs] : 0;
        __syncthreads();
        s[tid] += t;
        __syncthreads();
    }
    if (g < NN) part[g] = s[tid] - v;           // exclusive within block
    if (tid == 1023) bsum[blockIdx.x] = s[1023];
}

__global__ void k_scanB(int* __restrict__ bsum) {
    __shared__ int s[64];
    int tid = threadIdx.x;
    int v = (tid < NB) ? bsum[tid] : 0;
    s[tid] = v;
    __syncthreads();
    for (int ofs = 1; ofs < 64; ofs <<= 1) {
        int t = (tid >= ofs) ? s[tid - ofs] : 0;
        __syncthreads();
        s[tid] += t;
        __syncthreads();
    }
    if (tid < NB) bsum[tid] = s[tid] - v;       // exclusive
}

__global__ void k_scanC(const int* __restrict__ part, const int* __restrict__ bsum, int* __restrict__ cursor) {
    int g = blockIdx.x * 256 + threadIdx.x;
    if (g < NN) cursor[g] = part[g] + bsum[g >> 10];
}

// reorder: single 8B scattered store per edge (int2 {from,to}) instead of two 4B
__global__ void k_reorder(const int* __restrict__ from_idx, const int* __restrict__ to_idx,
                          int* __restrict__ cursor, int2* __restrict__ est) {
    int e = blockIdx.x * 256 + threadIdx.x;
    if (e < NE) {
        int d = to_idx[e];
        int p = atomicAdd(&cursor[d], 1);
        est[p] = make_int2(from_idx[e], d);
    }
}

// ---------------- edge kernel v12: v11 compute (validated 177us) on int2 edge array ----------------
__global__ __launch_bounds__(128, 2) void k_edges(
    const u16* __restrict__ nf16, const int2* __restrict__ est,
    const u16* __restrict__ pW0, const float* __restrict__ b0,
    const u16* __restrict__ pW1, const float* __restrict__ b1,
    float* __restrict__ agg)
{
    __shared__ u16 sX[64 * XS];
    __shared__ int sDest[64];
    const int tid = threadIdx.x;
    const int lane = tid & 63;
    const int wave = tid >> 6;
    const int base = wave * 32;
    const int l15  = lane & 15;
    const int quad = lane >> 4;
    const int e0 = blockIdx.x * 64;

    if (tid < 64) sDest[tid] = est[e0 + tid].y;

    // hoist biases: 24 per-lane values into registers (validated v10 win)
    float bias0[16], bias1[8];
    #pragma unroll
    for (int nt = 0; nt < 16; ++nt) bias0[nt] = b0[nt * 16 + l15];
    #pragma unroll
    for (int nt = 0; nt < 8; ++nt)  bias1[nt] = b1[nt * 16 + l15];

    // stage gather: 64 rows x 32 chunks of 8 bf16 (16 B); to-side rows repeat (sorted) -> cache-hot
    #pragma unroll
    for (int i = 0; i < 16; ++i) {
        int c = i * 128 + tid;
        int r = c >> 5, j = c & 31;
        int2 ft = est[e0 + r];
        int node = (j < 16) ? ft.x : ft.y;
        *(u16x8*)(&sX[r * XS + j * 8]) = *(const u16x8*)(nf16 + node * DD + (j & 15) * 8);
    }
    __syncthreads();

    const int arow0 = (base + l15) * XS + quad * 8;

    // consume X fully into registers (A-frags), freeing sX rows for H (rows wave-private)
    bf16x8 a[2][8];
    #pragma unroll
    for (int mt = 0; mt < 2; ++mt)
        #pragma unroll
        for (int kt = 0; kt < 8; ++kt)
            a[mt][kt] = __builtin_bit_cast(bf16x8, *(const u16x8*)(&sX[arow0 + mt * 16 * XS + kt * 32]));

    // layer 0: H[64,256] = relu(X @ W0 + b0); pinned 2-deep B-frag pipeline (v11, validated)
    bf16x8 bA[8], bB[8];
    loadB(bA, pW0, 0, lane);
    #pragma unroll
    for (int np = 0; np < 8; ++np) {
        const int ntA = 2 * np, ntB = 2 * np + 1;
        loadB(bB, pW0, ntB, lane);
        __builtin_amdgcn_sched_barrier(0);
        f32x4 c0 = {0.f, 0.f, 0.f, 0.f}, c1 = {0.f, 0.f, 0.f, 0.f};
        #pragma unroll
        for (int kt = 0; kt < 8; ++kt) {
            c0 = __builtin_amdgcn_mfma_f32_16x16x32_bf16(a[0][kt], bA[kt], c0, 0, 0, 0);
            c1 = __builtin_amdgcn_mfma_f32_16x16x32_bf16(a[1][kt], bA[kt], c1, 0, 0, 0);
        }
        #pragma unroll
        for (int i = 0; i < 4; ++i) {
            sX[(base +      quad * 4 + i) * XS + ntA * 16 + l15] = f2bf(fmaxf(c0[i] + bias0[ntA], 0.f));
            sX[(base + 16 + quad * 4 + i) * XS + ntA * 16 + l15] = f2bf(fmaxf(c1[i] + bias0[ntA], 0.f));
        }
        if (np < 7) {
            loadB(bA, pW0, ntA + 2, lane);
            __builtin_amdgcn_sched_barrier(0);
        }
        f32x4 d0 = {0.f, 0.f, 0.f, 0.f}, d1 = {0.f, 0.f, 0.f, 0.f};
        #pragma unroll
        for (int kt = 0; kt < 8; ++kt) {
            d0 = __builtin_amdgcn_mfma_f32_16x16x32_bf16(a[0][kt], bB[kt], d0, 0, 0, 0);
            d1 = __builtin_amdgcn_mfma_f32_16x16x32_bf16(a[1][kt], bB[kt], d1, 0, 0, 0);
        }
        #pragma unroll
        for (int i = 0; i < 4; ++i) {
            sX[(base +      quad * 4 + i) * XS + ntB * 16 + l15] = f2bf(fmaxf(d0[i] + bias0[ntB], 0.f));
            sX[(base + 16 + quad * 4 + i) * XS + ntB * 16 + l15] = f2bf(fmaxf(d1[i] + bias0[ntB], 0.f));
        }
    }

    // layer 1 A-frags from H (same rows, in-wave ordered: no barrier needed)
    #pragma unroll
    for (int mt = 0; mt < 2; ++mt)
        #pragma unroll
        for (int kt = 0; kt < 8; ++kt)
            a[mt][kt] = __builtin_bit_cast(bf16x8, *(const u16x8*)(&sX[arow0 + mt * 16 * XS + kt * 32]));

    __syncthreads();   // fence: u16 H-reads above must complete before fp32 m-writes below (TBAA)

    // layer 1: m = relu(H @ W1 + b1) -> fp32 into sM (reuses sX bytes; rows wave-private)
    float* sM = (float*)sX;   // [64][132] fp32 view, 132*4 = 264*2 bytes ✓
    loadB(bA, pW1, 0, lane);
    #pragma unroll
    for (int np = 0; np < 4; ++np) {
        const int ntA = 2 * np, ntB = 2 * np + 1;
        loadB(bB, pW1, ntB, lane);
        __builtin_amdgcn_sched_barrier(0);
        f32x4 c0 = {0.f, 0.f, 0.f, 0.f}, c1 = {0.f, 0.f, 0.f, 0.f};
        #pragma unroll
        for (int kt = 0; kt < 8; ++kt) {
            c0 = __builtin_amdgcn_mfma_f32_16x16x32_bf16(a[0][kt], bA[kt], c0, 0, 0, 0);
            c1 = __builtin_amdgcn_mfma_f32_16x16x32_bf16(a[1][kt], bA[kt], c1, 0, 0, 0);
        }
        #pragma unroll
        for (int i = 0; i < 4; ++i) {
            sM[(base +      quad * 4 + i) * 132 + ntA * 16 + l15] = fmaxf(c0[i] + bias1[ntA], 0.f);
            sM[(base + 16 + quad * 4 + i) * 132 + ntA * 16 + l15] = fmaxf(c1[i] + bias1[ntA], 0.f);
        }
        if (np < 3) {
            loadB(bA, pW1, ntA + 2, lane);
            __builtin_amdgcn_sched_barrier(0);
        }
        f32x4 d0 = {0.f, 0.f, 0.f, 0.f}, d1 = {0.f, 0.f, 0.f, 0.f};
        #pragma unroll
        for (int kt = 0; kt < 8; ++kt) {
            d0 = __builtin_amdgcn_mfma_f32_16x16x32_bf16(a[0][kt], bB[kt], d0, 0, 0, 0);
            d1 = __builtin_amdgcn_mfma_f32_16x16x32_bf16(a[1][kt], bB[kt], d1, 0, 0, 0);
        }
        #pragma unroll
        for (int i = 0; i < 4; ++i) {
            sM[(base +      quad * 4 + i) * 132 + ntB * 16 + l15] = fmaxf(d0[i] + bias1[ntB], 0.f);
            sM[(base + 16 + quad * 4 + i) * 132 + ntB * 16 + l15] = fmaxf(d1[i] + bias1[ntB], 0.f);
        }
    }
    __syncthreads();

    // block-wide segmented reduction over 64 sorted rows; thread = column (128 cols)
    const int head_d = sDest[0];
    const int tail_d = sDest[63];
    const bool head_sh = (e0 > 0) && (est[e0 - 1].y == head_d);
    const bool tail_sh = (e0 + 64 < NE) && (est[e0 + 64].y == tail_d);

    int dprev = head_d;
    float acc = sM[tid];          // row 0
    for (int r = 1; r < 64; ++r) {
        int d = sDest[r];         // wave-uniform -> uniform branch
        float v = sM[r * 132 + tid];
        if (d == dprev) acc += v;
        else {
            if ((dprev == head_d && head_sh) || (dprev == tail_d && tail_sh))
                unsafeAtomicAdd(&agg[(size_t)dprev * DD + tid], acc);
            else
                agg[(size_t)dprev * DD + tid] = acc;   // sole writer (interior run)
            acc = v; dprev = d;
        }
    }
    if ((dprev == head_d && head_sh) || (dprev == tail_d && tail_sh))
        unsafeAtomicAdd(&agg[(size_t)dprev * DD + tid], acc);
    else
        agg[(size_t)dprev * DD + tid] = acc;
}

// Node update: v11 (validated) unchanged
__global__ __launch_bounds__(128, 2) void k_update(
    const float* __restrict__ agg, const u16* __restrict__ nf16,
    const float* __restrict__ nf32, const u16* __restrict__ pW0,
    const float* __restrict__ b0, const u16* __restrict__ pW1,
    const float* __restrict__ b1, float* __restrict__ out)
{
    __shared__ u16 sX[64 * XS];
    const int tid = threadIdx.x;
    const int lane = tid & 63;
    const int wave = tid >> 6;
    const int base = wave * 32;
    const int l15  = lane & 15;
    const int quad = lane >> 4;
    const int n0 = blockIdx.x * 64;

    float bias0[16], bias1[8];
    #pragma unroll
    for (int nt = 0; nt < 16; ++nt) bias0[nt] = b0[nt * 16 + l15];
    #pragma unroll
    for (int nt = 0; nt < 8; ++nt)  bias1[nt] = b1[nt * 16 + l15];

    // stage agg half (cols 0..127), fp32->bf16
    #pragma unroll
    for (int i = 0; i < 16; ++i) {
        int c = i * 128 + tid;
        int r = c >> 5, j = c & 31;
        int n = n0 + r;
        u16x4 o;
        if (n < NN) {
            float4 v = *(const float4*)(agg + (size_t)n * DD + j * 4);
            o[0] = f2bf(v.x); o[1] = f2bf(v.y); o[2] = f2bf(v.z); o[3] = f2bf(v.w);
        } else { o[0] = 0; o[1] = 0; o[2] = 0; o[3] = 0; }
        *(u16x4*)(&sX[r * XS + j * 4]) = o;
    }
    // stage nf half (cols 128..255), bf16 copy
    #pragma unroll
    for (int i = 0; i < 8; ++i) {
        int c = i * 128 + tid;
        int r = c >> 4, j = c & 15;
        int n = n0 + r;
        u16x8 v = {0, 0, 0, 0, 0, 0, 0, 0};
        if (n < NN) v = *(const u16x8*)(nf16 + (size_t)n * DD + j * 8);
        *(u16x8*)(&sX[r * XS + 128 + j * 8]) = v;
    }
    __syncthreads();

    const int arow0 = (base + l15) * XS + quad * 8;

    bf16x8 a[2][8];
    #pragma unroll
    for (int mt = 0; mt < 2; ++mt)
        #pragma unroll
        for (int kt = 0; kt < 8; ++kt)
            a[mt][kt] = __builtin_bit_cast(bf16x8, *(const u16x8*)(&sX[arow0 + mt * 16 * XS + kt * 32]));

    bf16x8 bA[8], bB[8];
    loadB(bA, pW0, 0, lane);
    #pragma unroll
    for (int np = 0; np < 8; ++np) {
        const int ntA = 2 * np, ntB = 2 * np + 1;
        loadB(bB, pW0, ntB, lane);
        __builtin_amdgcn_sched_barrier(0);
        f32x4 c0 = {0.f, 0.f, 0.f, 0.f}, c1 = {0.f, 0.f, 0.f, 0.f};
        #pragma unroll
        for (int kt = 0; kt < 8; ++kt) {
            c0 = __builtin_amdgcn_mfma_f32_16x16x32_bf16(a[0][kt], bA[kt], c0, 0, 0, 0);
            c1 = __builtin_amdgcn_mfma_f32_16x16x32_bf16(a[1][kt], bA[kt], c1, 0, 0, 0);
        }
        #pragma unroll
        for (int i = 0; i < 4; ++i) {
            sX[(base +      quad * 4 + i) * XS + ntA * 16 + l15] = f2bf(fmaxf(c0[i] + bias0[ntA], 0.f));
            sX[(base + 16 + quad * 4 + i) * XS + ntA * 16 + l15] = f2bf(fmaxf(c1[i] + bias0[ntA], 0.f));
        }
        if (np < 7) {
            loadB(bA, pW0, ntA + 2, lane);
            __builtin_amdgcn_sched_barrier(0);
        }
        f32x4 d0 = {0.f, 0.f, 0.f, 0.f}, d1 = {0.f, 0.f, 0.f, 0.f};
        #pragma unroll
        for (int kt = 0; kt < 8; ++kt) {
            d0 = __builtin_amdgcn_mfma_f32_16x16x32_bf16(a[0][kt], bB[kt], d0, 0, 0, 0);
            d1 = __builtin_amdgcn_mfma_f32_16x16x32_bf16(a[1][kt], bB[kt], d1, 0, 0, 0);
        }
        #pragma unroll
        for (int i = 0; i < 4; ++i) {
            sX[(base +      quad * 4 + i) * XS + ntB * 16 + l15] = f2bf(fmaxf(d0[i] + bias0[ntB], 0.f));
            sX[(base + 16 + quad * 4 + i) * XS + ntB * 16 + l15] = f2bf(fmaxf(d1[i] + bias0[ntB], 0.f));
        }
    }

    #pragma unroll
    for (int mt = 0; mt < 2; ++mt)
        #pragma unroll
        for (int kt = 0; kt < 8; ++kt)
            a[mt][kt] = __builtin_bit_cast(bf16x8, *(const u16x8*)(&sX[arow0 + mt * 16 * XS + kt * 32]));

    loadB(bA, pW1, 0, lane);
    #pragma unroll
    for (int np = 0; np < 4; ++np) {
        const int ntA = 2 * np, ntB = 2 * np + 1;
        loadB(bB, pW1, ntB, lane);
        __builtin_amdgcn_sched_barrier(0);
        f32x4 c0 = {0.f, 0.f, 0.f, 0.f}, c1 = {0.f, 0.f, 0.f, 0.f};
        #pragma unroll
        for (int kt = 0; kt < 8; ++kt) {
            c0 = __builtin_amdgcn_mfma_f32_16x16x32_bf16(a[0][kt], bA[kt], c0, 0, 0, 0);
            c1 = __builtin_amdgcn_mfma_f32_16x16x32_bf16(a[1][kt], bA[kt], c1, 0, 0, 0);
        }
        {
            int col = ntA * 16 + l15;
            #pragma unroll
            for (int i = 0; i < 4; ++i) {
                int na = n0 + base +      quad * 4 + i;
                int nb = n0 + base + 16 + quad * 4 + i;
                if (na < NN) out[(size_t)na * DD + col] = nf32[(size_t)na * DD + col] + fmaxf(c0[i] + bias1[ntA], 0.f);
                if (nb < NN) out[(size_t)nb * DD + col] = nf32[(size_t)nb * DD + col] + fmaxf(c1[i] + bias1[ntA], 0.f);
            }
        }
        if (np < 3) {
            loadB(bA, pW1, ntA + 2, lane);
            __builtin_amdgcn_sched_barrier(0);
        }
        f32x4 d0 = {0.f, 0.f, 0.f, 0.f}, d1 = {0.f, 0.f, 0.f, 0.f};
        #pragma unroll
        for (int kt = 0; kt < 8; ++kt) {
            d0 = __builtin_amdgcn_mfma_f32_16x16x32_bf16(a[0][kt], bB[kt], d0, 0, 0, 0);
            d1 = __builtin_amdgcn_mfma_f32_16x16x32_bf16(a[1][kt], bB[kt], d1, 0, 0, 0);
        }
        {
            int col = ntB * 16 + l15;
            #pragma unroll
            for (int i = 0; i < 4; ++i) {
                int na = n0 + base +      quad * 4 + i;
                int nb = n0 + base + 16 + quad * 4 + i;
                if (na < NN) out[(size_t)na * DD + col] = nf32[(size_t)na * DD + col] + fmaxf(d0[i] + bias1[ntB], 0.f);
                if (nb < NN) out[(size_t)nb * DD + col] = nf32[(size_t)nb * DD + col] + fmaxf(d1[i] + bias1[ntB], 0.f);
            }
        }
    }
}

extern "C" void kernel_launch(void* const* d_in, const int* in_sizes, int n_in,
                              void* d_out, int out_size, void* d_ws, size_t ws_size,
                              hipStream_t stream)
{
    const float* nf  = (const float*)d_in[0];
    const int* fidx  = (const int*)d_in[1];
    const int* tidx  = (const int*)d_in[2];
    const float* mW0 = (const float*)d_in[3];
    const float* mb0 = (const float*)d_in[4];
    const float* mW1 = (const float*)d_in[5];
    const float* mb1 = (const float*)d_in[6];
    const float* uW0 = (const float*)d_in[7];
    const float* ub0 = (const float*)d_in[8];
    const float* uW1 = (const float*)d_in[9];
    const float* ub1 = (const float*)d_in[10];
    float* out = (float*)d_out;

    char* ws = (char*)d_ws;
    u16*   nf16 = (u16*)ws;   ws += (size_t)NN * DD * 2;   // 12.8 MB
    float* agg  = (float*)ws; ws += (size_t)NN * DD * 4;   // 25.6 MB
    u16*   pmW0 = (u16*)ws;   ws += 256 * 256 * 2;
    u16*   pmW1 = (u16*)ws;   ws += 256 * 128 * 2;
    u16*   puW0 = (u16*)ws;   ws += 256 * 256 * 2;
    u16*   puW1 = (u16*)ws;   ws += 256 * 128 * 2;
    int*   cnt    = (int*)ws; ws += (size_t)NN * 4;        // 0.2 MB
    int*   cursor = (int*)ws; ws += (size_t)NN * 4;        // 0.2 MB
    int*   part   = (int*)ws; ws += (size_t)NN * 4;        // 0.2 MB
    int*   bsum   = (int*)ws; ws += 64 * 4;
    int2*  est    = (int2*)ws; ws += (size_t)NE * 8;       // 4.8 MB (sorted {from,to})

    hipMemsetAsync(agg, 0, (size_t)NN * DD * 4, stream);
    hipMemsetAsync(cnt, 0, (size_t)NN * 4, stream);
    k_prep<<<9362, 256, 0, stream>>>(nf, nf16, tidx, cnt, mW0, pmW0, mW1, pmW1, uW0, puW0, uW1, puW1);
    k_scanA<<<NB, 1024, 0, stream>>>(cnt, part, bsum);
    k_scanB<<<1, 64, 0, stream>>>(bsum);
    k_scanC<<<(NN + 255) / 256, 256, 0, stream>>>(part, bsum, cursor);
    k_reorder<<<(NE + 255) / 256, 256, 0, stream>>>(fidx, tidx, cursor, est);
    k_edges<<<NE / 64, 128, 0, stream>>>(nf16, est, pmW0, mb0, pmW1, mb1, agg);
    k_update<<<(NN + 63) / 64, 128, 0, stream>>>(agg, nf16, nf, puW0, ub0, puW1, ub1, out);
}

// Round 15
// 358.638 us; speedup vs baseline: 1.3249x; 1.0045x over previous
//
#include <hip/hip_runtime.h>

#define NN 50000
#define NE 600000
#define DD 128
#define XS 264   // padded LDS row stride in bf16 elems: 528 B = 132 fp32 (exact fp32 reuse for m-buffer)
#define NB 49    // scan blocks: ceil(NN/1024)

typedef unsigned short u16;
typedef u16   u16x8  __attribute__((ext_vector_type(8)));
typedef u16   u16x4  __attribute__((ext_vector_type(4)));
typedef __bf16 bf16x8 __attribute__((ext_vector_type(8)));
typedef float f32x4  __attribute__((ext_vector_type(4)));

__device__ __forceinline__ u16 f2bf(float f) {  // RNE fp32->bf16
    unsigned u = __builtin_bit_cast(unsigned, f);
    u += 0x7FFFu + ((u >> 16) & 1u);
    return (u16)(u >> 16);
}

// load one nt-column of packed W into 8 named B-frag registers
__device__ __forceinline__ void loadB(bf16x8 (&d)[8], const u16* __restrict__ pw, int nt, int lane) {
    #pragma unroll
    for (int kt = 0; kt < 8; ++kt)
        d[kt] = __builtin_bit_cast(bf16x8, *(const u16x8*)(pw + (nt * 8 + kt) * 512 + lane * 8));
}

// pack one element of W[K,N] into MFMA B-fragment order (validated k_pack body)
__device__ __forceinline__ void pack_one(const float* __restrict__ W, u16* __restrict__ out,
                                         int K, int N, int tid) {
    int frag = tid >> 9, lane = (tid >> 3) & 63, j = tid & 7;
    int KT = K >> 5;
    int nt = frag / KT, kt = frag - nt * KT;
    int row = kt * 32 + ((lane >> 4) << 3) + j;
    int col = nt * 16 + (lane & 15);
    out[tid] = f2bf(W[row * N + col]);
}

// ---------------- fused prep: convert_nf + hist + 4x pack in one dispatch (validated r14) ----------------
__global__ void k_prep(const float* __restrict__ nf, u16* __restrict__ nf16,
                       const int* __restrict__ to_idx, int* __restrict__ cnt,
                       const float* __restrict__ mW0, u16* __restrict__ pmW0,
                       const float* __restrict__ mW1, u16* __restrict__ pmW1,
                       const float* __restrict__ uW0, u16* __restrict__ puW0,
                       const float* __restrict__ uW1, u16* __restrict__ puW1)
{
    const int b = blockIdx.x;
    const int tid = threadIdx.x;
    if (b < 6250) {                      // convert: NN*DD/4 = 1.6M float4 lanes
        int id = b * 256 + tid;
        float4 v = ((const float4*)nf)[id];
        u16x4 o; o[0] = f2bf(v.x); o[1] = f2bf(v.y); o[2] = f2bf(v.z); o[3] = f2bf(v.w);
        ((u16x4*)nf16)[id] = o;
    } else if (b < 6250 + 2344) {        // hist
        int e = (b - 6250) * 256 + tid;
        if (e < NE) atomicAdd(&cnt[to_idx[e]], 1);
    } else {                             // packs: g in [0, 196608)
        int g = (b - 8594) * 256 + tid;
        if (g < 65536)       pack_one(mW0, pmW0, 256, 256, g);
        else if (g < 98304)  pack_one(mW1, pmW1, 256, 128, g - 65536);
        else if (g < 163840) pack_one(uW0, puW0, 256, 256, g - 98304);
        else                 pack_one(uW1, puW1, 256, 128, g - 163840);
    }
}

// ---------------- counting-sort scan (scanB folded into scanC) ----------------
__global__ void k_scanA(const int* __restrict__ cnt, int* __restrict__ part, int* __restrict__ bsum) {
    __shared__ int s[1024];
    int tid = threadIdx.x;
    int g = blockIdx.x * 1024 + tid;
    int v = (g < NN) ? cnt[g] : 0;
    s[tid] = v;
    __syncthreads();
    for (int ofs = 1; ofs < 1024; ofs <<= 1) {
        int t = (tid >= ofs) ? s[tid - ofs] : 0;
        __syncthreads();
        s[tid] += t;
        __syncthreads();
    }
    if (g < NN) part[g] = s[tid] - v;           // exclusive within block
    if (tid == 1023) bsum[blockIdx.x] = s[1023];
}

// cursor = part + prefix(bsum) — prefix computed inline (49-iter wave-uniform loop, L2-hot)
__global__ void k_scanC(const int* __restrict__ part, const int* __restrict__ bsum, int* __restrict__ cursor) {
    int g = blockIdx.x * 256 + threadIdx.x;
    if (g < NN) {
        int blk = g >> 10;               // uniform within a 256-thread block (256 | 1024)
        int off = 0;
        for (int j = 0; j < blk; ++j) off += bsum[j];
        cursor[g] = part[g] + off;
    }
}

// reorder: single 8B scattered store per edge (int2 {from,to})
__global__ void k_reorder(const int* __restrict__ from_idx, const int* __restrict__ to_idx,
                          int* __restrict__ cursor, int2* __restrict__ est) {
    int e = blockIdx.x * 256 + threadIdx.x;
    if (e < NE) {
        int d = to_idx[e];
        int p = atomicAdd(&cursor[d], 1);
        est[p] = make_int2(from_idx[e], d);
    }
}

// ---------------- edge kernel v12 (validated 181us): unchanged ----------------
__global__ __launch_bounds__(128, 2) void k_edges(
    const u16* __restrict__ nf16, const int2* __restrict__ est,
    const u16* __restrict__ pW0, const float* __restrict__ b0,
    const u16* __restrict__ pW1, const float* __restrict__ b1,
    float* __restrict__ agg)
{
    __shared__ u16 sX[64 * XS];
    __shared__ int sDest[64];
    const int tid = threadIdx.x;
    const int lane = tid & 63;
    const int wave = tid >> 6;
    const int base = wave * 32;
    const int l15  = lane & 15;
    const int quad = lane >> 4;
    const int e0 = blockIdx.x * 64;

    if (tid < 64) sDest[tid] = est[e0 + tid].y;

    float bias0[16], bias1[8];
    #pragma unroll
    for (int nt = 0; nt < 16; ++nt) bias0[nt] = b0[nt * 16 + l15];
    #pragma unroll
    for (int nt = 0; nt < 8; ++nt)  bias1[nt] = b1[nt * 16 + l15];

    // stage gather: 64 rows x 32 chunks of 8 bf16 (16 B)
    #pragma unroll
    for (int i = 0; i < 16; ++i) {
        int c = i * 128 + tid;
        int r = c >> 5, j = c & 31;
        int2 ft = est[e0 + r];
        int node = (j < 16) ? ft.x : ft.y;
        *(u16x8*)(&sX[r * XS + j * 8]) = *(const u16x8*)(nf16 + node * DD + (j & 15) * 8);
    }
    __syncthreads();

    const int arow0 = (base + l15) * XS + quad * 8;

    bf16x8 a[2][8];
    #pragma unroll
    for (int mt = 0; mt < 2; ++mt)
        #pragma unroll
        for (int kt = 0; kt < 8; ++kt)
            a[mt][kt] = __builtin_bit_cast(bf16x8, *(const u16x8*)(&sX[arow0 + mt * 16 * XS + kt * 32]));

    // layer 0: pinned 2-deep B-frag pipeline (v11, validated)
    bf16x8 bA[8], bB[8];
    loadB(bA, pW0, 0, lane);
    #pragma unroll
    for (int np = 0; np < 8; ++np) {
        const int ntA = 2 * np, ntB = 2 * np + 1;
        loadB(bB, pW0, ntB, lane);
        __builtin_amdgcn_sched_barrier(0);
        f32x4 c0 = {0.f, 0.f, 0.f, 0.f}, c1 = {0.f, 0.f, 0.f, 0.f};
        #pragma unroll
        for (int kt = 0; kt < 8; ++kt) {
            c0 = __builtin_amdgcn_mfma_f32_16x16x32_bf16(a[0][kt], bA[kt], c0, 0, 0, 0);
            c1 = __builtin_amdgcn_mfma_f32_16x16x32_bf16(a[1][kt], bA[kt], c1, 0, 0, 0);
        }
        #pragma unroll
        for (int i = 0; i < 4; ++i) {
            sX[(base +      quad * 4 + i) * XS + ntA * 16 + l15] = f2bf(fmaxf(c0[i] + bias0[ntA], 0.f));
            sX[(base + 16 + quad * 4 + i) * XS + ntA * 16 + l15] = f2bf(fmaxf(c1[i] + bias0[ntA], 0.f));
        }
        if (np < 7) {
            loadB(bA, pW0, ntA + 2, lane);
            __builtin_amdgcn_sched_barrier(0);
        }
        f32x4 d0 = {0.f, 0.f, 0.f, 0.f}, d1 = {0.f, 0.f, 0.f, 0.f};
        #pragma unroll
        for (int kt = 0; kt < 8; ++kt) {
            d0 = __builtin_amdgcn_mfma_f32_16x16x32_bf16(a[0][kt], bB[kt], d0, 0, 0, 0);
            d1 = __builtin_amdgcn_mfma_f32_16x16x32_bf16(a[1][kt], bB[kt], d1, 0, 0, 0);
        }
        #pragma unroll
        for (int i = 0; i < 4; ++i) {
            sX[(base +      quad * 4 + i) * XS + ntB * 16 + l15] = f2bf(fmaxf(d0[i] + bias0[ntB], 0.f));
            sX[(base + 16 + quad * 4 + i) * XS + ntB * 16 + l15] = f2bf(fmaxf(d1[i] + bias0[ntB], 0.f));
        }
    }

    #pragma unroll
    for (int mt = 0; mt < 2; ++mt)
        #pragma unroll
        for (int kt = 0; kt < 8; ++kt)
            a[mt][kt] = __builtin_bit_cast(bf16x8, *(const u16x8*)(&sX[arow0 + mt * 16 * XS + kt * 32]));

    __syncthreads();   // fence: u16 H-reads above must complete before fp32 m-writes below (TBAA)

    float* sM = (float*)sX;   // [64][132] fp32 view
    loadB(bA, pW1, 0, lane);
    #pragma unroll
    for (int np = 0; np < 4; ++np) {
        const int ntA = 2 * np, ntB = 2 * np + 1;
        loadB(bB, pW1, ntB, lane);
        __builtin_amdgcn_sched_barrier(0);
        f32x4 c0 = {0.f, 0.f, 0.f, 0.f}, c1 = {0.f, 0.f, 0.f, 0.f};
        #pragma unroll
        for (int kt = 0; kt < 8; ++kt) {
            c0 = __builtin_amdgcn_mfma_f32_16x16x32_bf16(a[0][kt], bA[kt], c0, 0, 0, 0);
            c1 = __builtin_amdgcn_mfma_f32_16x16x32_bf16(a[1][kt], bA[kt], c1, 0, 0, 0);
        }
        #pragma unroll
        for (int i = 0; i < 4; ++i) {
            sM[(base +      quad * 4 + i) * 132 + ntA * 16 + l15] = fmaxf(c0[i] + bias1[ntA], 0.f);
            sM[(base + 16 + quad * 4 + i) * 132 + ntA * 16 + l15] = fmaxf(c1[i] + bias1[ntA], 0.f);
        }
        if (np < 3) {
            loadB(bA, pW1, ntA + 2, lane);
            __builtin_amdgcn_sched_barrier(0);
        }
        f32x4 d0 = {0.f, 0.f, 0.f, 0.f}, d1 = {0.f, 0.f, 0.f, 0.f};
        #pragma unroll
        for (int kt = 0; kt < 8; ++kt) {
            d0 = __builtin_amdgcn_mfma_f32_16x16x32_bf16(a[0][kt], bB[kt], d0, 0, 0, 0);
            d1 = __builtin_amdgcn_mfma_f32_16x16x32_bf16(a[1][kt], bB[kt], d1, 0, 0, 0);
        }
        #pragma unroll
        for (int i = 0; i < 4; ++i) {
            sM[(base +      quad * 4 + i) * 132 + ntB * 16 + l15] = fmaxf(d0[i] + bias1[ntB], 0.f);
            sM[(base + 16 + quad * 4 + i) * 132 + ntB * 16 + l15] = fmaxf(d1[i] + bias1[ntB], 0.f);
        }
    }
    __syncthreads();

    // block-wide segmented reduction over 64 sorted rows; thread = column (128 cols)
    const int head_d = sDest[0];
    const int tail_d = sDest[63];
    const bool head_sh = (e0 > 0) && (est[e0 - 1].y == head_d);
    const bool tail_sh = (e0 + 64 < NE) && (est[e0 + 64].y == tail_d);

    int dprev = head_d;
    float acc = sM[tid];          // row 0
    for (int r = 1; r < 64; ++r) {
        int d = sDest[r];
        float v = sM[r * 132 + tid];
        if (d == dprev) acc += v;
        else {
            if ((dprev == head_d && head_sh) || (dprev == tail_d && tail_sh))
                unsafeAtomicAdd(&agg[(size_t)dprev * DD + tid], acc);
            else
                agg[(size_t)dprev * DD + tid] = acc;
            acc = v; dprev = d;
        }
    }
    if ((dprev == head_d && head_sh) || (dprev == tail_d && tail_sh))
        unsafeAtomicAdd(&agg[(size_t)dprev * DD + tid], acc);
    else
        agg[(size_t)dprev * DD + tid] = acc;
}

// ---------------- node update v13: 1-wave / 32-row blocks, barrier-free ----------------
// Old: 782 blocks -> ~3/CU, one residency round, duration = one block's serial latency chain.
// New: 1563 blocks x 1 wave (LDS 16.9KB -> ~9 blocks/CU), no __syncthreads (single wave,
// in-order DS pipe). Per-wave compute identical (2 m-tiles, pinned pipeline, hoisted biases).
__global__ __launch_bounds__(64, 2) void k_update(
    const float* __restrict__ agg, const u16* __restrict__ nf16,
    const float* __restrict__ nf32, const u16* __restrict__ pW0,
    const float* __restrict__ b0, const u16* __restrict__ pW1,
    const float* __restrict__ b1, float* __restrict__ out)
{
    __shared__ u16 sX[32 * XS];   // 16,896 B
    const int lane = threadIdx.x; // 64 threads = 1 wave
    const int l15  = lane & 15;
    const int quad = lane >> 4;
    const int n0 = blockIdx.x * 32;

    float bias0[16], bias1[8];
    #pragma unroll
    for (int nt = 0; nt < 16; ++nt) bias0[nt] = b0[nt * 16 + l15];
    #pragma unroll
    for (int nt = 0; nt < 8; ++nt)  bias1[nt] = b1[nt * 16 + l15];

    // stage agg half (cols 0..127), fp32->bf16: 32 rows x 32 chunks / 64 lanes = 16 iters
    #pragma unroll
    for (int i = 0; i < 16; ++i) {
        int c = i * 64 + lane;
        int r = c >> 5, j = c & 31;
        int n = n0 + r;
        u16x4 o;
        if (n < NN) {
            float4 v = *(const float4*)(agg + (size_t)n * DD + j * 4);
            o[0] = f2bf(v.x); o[1] = f2bf(v.y); o[2] = f2bf(v.z); o[3] = f2bf(v.w);
        } else { o[0] = 0; o[1] = 0; o[2] = 0; o[3] = 0; }
        *(u16x4*)(&sX[r * XS + j * 4]) = o;
    }
    // stage nf half (cols 128..255): 32 rows x 16 chunks / 64 lanes = 8 iters
    #pragma unroll
    for (int i = 0; i < 8; ++i) {
        int c = i * 64 + lane;
        int r = c >> 4, j = c & 15;
        int n = n0 + r;
        u16x8 v = {0, 0, 0, 0, 0, 0, 0, 0};
        if (n < NN) v = *(const u16x8*)(nf16 + (size_t)n * DD + j * 8);
        *(u16x8*)(&sX[r * XS + 128 + j * 8]) = v;
    }
    // no barrier: single wave, in-order DS pipe

    const int arow0 = l15 * XS + quad * 8;

    bf16x8 a[2][8];
    #pragma unroll
    for (int mt = 0; mt < 2; ++mt)
        #pragma unroll
        for (int kt = 0; kt < 8; ++kt)
            a[mt][kt] = __builtin_bit_cast(bf16x8, *(const u16x8*)(&sX[arow0 + mt * 16 * XS + kt * 32]));

    bf16x8 bA[8], bB[8];
    loadB(bA, pW0, 0, lane);
    #pragma unroll
    for (int np = 0; np < 8; ++np) {
        const int ntA = 2 * np, ntB = 2 * np + 1;
        loadB(bB, pW0, ntB, lane);
        __builtin_amdgcn_sched_barrier(0);
        f32x4 c0 = {0.f, 0.f, 0.f, 0.f}, c1 = {0.f, 0.f, 0.f, 0.f};
        #pragma unroll
        for (int kt = 0; kt < 8; ++kt) {
            c0 = __builtin_amdgcn_mfma_f32_16x16x32_bf16(a[0][kt], bA[kt], c0, 0, 0, 0);
            c1 = __builtin_amdgcn_mfma_f32_16x16x32_bf16(a[1][kt], bA[kt], c1, 0, 0, 0);
        }
        #pragma unroll
        for (int i = 0; i < 4; ++i) {
            sX[(     quad * 4 + i) * XS + ntA * 16 + l15] = f2bf(fmaxf(c0[i] + bias0[ntA], 0.f));
            sX[(16 + quad * 4 + i) * XS + ntA * 16 + l15] = f2bf(fmaxf(c1[i] + bias0[ntA], 0.f));
        }
        if (np < 7) {
            loadB(bA, pW0, ntA + 2, lane);
            __builtin_amdgcn_sched_barrier(0);
        }
        f32x4 d0 = {0.f, 0.f, 0.f, 0.f}, d1 = {0.f, 0.f, 0.f, 0.f};
        #pragma unroll
        for (int kt = 0; kt < 8; ++kt) {
            d0 = __builtin_amdgcn_mfma_f32_16x16x32_bf16(a[0][kt], bB[kt], d0, 0, 0, 0);
            d1 = __builtin_amdgcn_mfma_f32_16x16x32_bf16(a[1][kt], bB[kt], d1, 0, 0, 0);
        }
        #pragma unroll
        for (int i = 0; i < 4; ++i) {
            sX[(     quad * 4 + i) * XS + ntB * 16 + l15] = f2bf(fmaxf(d0[i] + bias0[ntB], 0.f));
            sX[(16 + quad * 4 + i) * XS + ntB * 16 + l15] = f2bf(fmaxf(d1[i] + bias0[ntB], 0.f));
        }
    }

    #pragma unroll
    for (int mt = 0; mt < 2; ++mt)
        #pragma unroll
        for (int kt = 0; kt < 8; ++kt)
            a[mt][kt] = __builtin_bit_cast(bf16x8, *(const u16x8*)(&sX[arow0 + mt * 16 * XS + kt * 32]));

    loadB(bA, pW1, 0, lane);
    #pragma unroll
    for (int np = 0; np < 4; ++np) {
        const int ntA = 2 * np, ntB = 2 * np + 1;
        loadB(bB, pW1, ntB, lane);
        __builtin_amdgcn_sched_barrier(0);
        f32x4 c0 = {0.f, 0.f, 0.f, 0.f}, c1 = {0.f, 0.f, 0.f, 0.f};
        #pragma unroll
        for (int kt = 0; kt < 8; ++kt) {
            c0 = __builtin_amdgcn_mfma_f32_16x16x32_bf16(a[0][kt], bA[kt], c0, 0, 0, 0);
            c1 = __builtin_amdgcn_mfma_f32_16x16x32_bf16(a[1][kt], bA[kt], c1, 0, 0, 0);
        }
        {
            int col = ntA * 16 + l15;
            #pragma unroll
            for (int i = 0; i < 4; ++i) {
                int na = n0 +      quad * 4 + i;
                int nb = n0 + 16 + quad * 4 + i;
                if (na < NN) out[(size_t)na * DD + col] = nf32[(size_t)na * DD + col] + fmaxf(c0[i] + bias1[ntA], 0.f);
                if (nb < NN) out[(size_t)nb * DD + col] = nf32[(size_t)nb * DD + col] + fmaxf(c1[i] + bias1[ntA], 0.f);
            }
        }
        if (np < 3) {
            loadB(bA, pW1, ntA + 2, lane);
            __builtin_amdgcn_sched_barrier(0);
        }
        f32x4 d0 = {0.f, 0.f, 0.f, 0.f}, d1 = {0.f, 0.f, 0.f, 0.f};
        #pragma unroll
        for (int kt = 0; kt < 8; ++kt) {
            d0 = __builtin_amdgcn_mfma_f32_16x16x32_bf16(a[0][kt], bB[kt], d0, 0, 0, 0);
            d1 = __builtin_amdgcn_mfma_f32_16x16x32_bf16(a[1][kt], bB[kt], d1, 0, 0, 0);
        }
        {
            int col = ntB * 16 + l15;
            #pragma unroll
            for (int i = 0; i < 4; ++i) {
                int na = n0 +      quad * 4 + i;
                int nb = n0 + 16 + quad * 4 + i;
                if (na < NN) out[(size_t)na * DD + col] = nf32[(size_t)na * DD + col] + fmaxf(d0[i] + bias1[ntB], 0.f);
                if (nb < NN) out[(size_t)nb * DD + col] = nf32[(size_t)nb * DD + col] + fmaxf(d1[i] + bias1[ntB], 0.f);
            }
        }
    }
}

extern "C" void kernel_launch(void* const* d_in, const int* in_sizes, int n_in,
                              void* d_out, int out_size, void* d_ws, size_t ws_size,
                              hipStream_t stream)
{
    const float* nf  = (const float*)d_in[0];
    const int* fidx  = (const int*)d_in[1];
    const int* tidx  = (const int*)d_in[2];
    const float* mW0 = (const float*)d_in[3];
    const float* mb0 = (const float*)d_in[4];
    const float* mW1 = (const float*)d_in[5];
    const float* mb1 = (const float*)d_in[6];
    const float* uW0 = (const float*)d_in[7];
    const float* ub0 = (const float*)d_in[8];
    const float* uW1 = (const float*)d_in[9];
    const float* ub1 = (const float*)d_in[10];
    float* out = (float*)d_out;

    char* ws = (char*)d_ws;
    u16*   nf16 = (u16*)ws;   ws += (size_t)NN * DD * 2;   // 12.8 MB
    float* agg  = (float*)ws; ws += (size_t)NN * DD * 4;   // 25.6 MB
    u16*   pmW0 = (u16*)ws;   ws += 256 * 256 * 2;
    u16*   pmW1 = (u16*)ws;   ws += 256 * 128 * 2;
    u16*   puW0 = (u16*)ws;   ws += 256 * 256 * 2;
    u16*   puW1 = (u16*)ws;   ws += 256 * 128 * 2;
    int*   cnt    = (int*)ws; ws += (size_t)NN * 4;        // 0.2 MB
    int*   cursor = (int*)ws; ws += (size_t)NN * 4;        // 0.2 MB
    int*   part   = (int*)ws; ws += (size_t)NN * 4;        // 0.2 MB
    int*   bsum   = (int*)ws; ws += 64 * 4;
    int2*  est    = (int2*)ws; ws += (size_t)NE * 8;       // 4.8 MB (sorted {from,to})

    hipMemsetAsync(agg, 0, (size_t)NN * DD * 4, stream);
    hipMemsetAsync(cnt, 0, (size_t)NN * 4, stream);
    k_prep<<<9362, 256, 0, stream>>>(nf, nf16, tidx, cnt, mW0, pmW0, mW1, pmW1, uW0, puW0, uW1, puW1);
    k_scanA<<<NB, 1024, 0, stream>>>(cnt, part, bsum);
    k_scanC<<<(NN + 255) / 256, 256, 0, stream>>>(part, bsum, cursor);
    k_reorder<<<(NE + 255) / 256, 256, 0, stream>>>(fidx, tidx, cursor, est);
    k_edges<<<NE / 64, 128, 0, stream>>>(nf16, est, pmW0, mb0, pmW1, mb1, agg);
    k_update<<<(NN + 31) / 32, 64, 0, stream>>>(agg, nf16, nf, puW0, ub0, puW1, ub1, out);
}